// Round 1
// baseline (417.651 us; speedup 1.0000x reference)
//
#include <hip/hip_runtime.h>
#include <hip/hip_bf16.h>
#include <cstdint>
#include <cstddef>

#define S_LEN  1024
#define DMODEL 1024
#define NHEAD  16
#define HDIM   64
#define BATCH  4
#define MROWS  (BATCH * S_LEN)   // 4096

typedef __bf16 bf16;
typedef __attribute__((ext_vector_type(8))) __bf16 bf16x8;
typedef __attribute__((ext_vector_type(4))) __bf16 bf16x4;
typedef __attribute__((ext_vector_type(4))) float f32x4;
typedef __attribute__((ext_vector_type(4))) unsigned int u32x4;

// ---------------------------------------------------------------------------
// async global->LDS, 16B per lane. LDS dest must be wave-uniform base.
__device__ __forceinline__ void async_load16(const void* g, void* l) {
    __builtin_amdgcn_global_load_lds(
        (const __attribute__((address_space(1))) unsigned int*)g,
        (__attribute__((address_space(3))) unsigned int*)l,
        16, 0, 0);
}

// ---------------------------------------------------------------------------
// f32 -> bf16 elementwise convert (vectorized x4)
__global__ __launch_bounds__(256)
void cvt_f32_bf16(const float* __restrict__ in, bf16* __restrict__ out, int n4) {
    int i = blockIdx.x * 256 + threadIdx.x;
    if (i >= n4) return;
    f32x4 v = ((const f32x4*)in)[i];
    bf16x4 o;
#pragma unroll
    for (int e = 0; e < 4; ++e) o[e] = (bf16)v[e];
    ((bf16x4*)out)[i] = o;
}

// ---------------------------------------------------------------------------
// W[K][N] f32  ->  Wt[N][K] bf16   (LDS-tiled transpose, 32x32 tiles)
__global__ __launch_bounds__(256)
void wconv(const float* __restrict__ W, bf16* __restrict__ Wt, int K, int N) {
    __shared__ float t[32][33];
    int n0 = blockIdx.x * 32, k0 = blockIdx.y * 32;
    int tx = threadIdx.x & 31, ty = threadIdx.x >> 5;  // 32 x 8
#pragma unroll
    for (int j = 0; j < 4; ++j)
        t[ty + j * 8][tx] = W[(size_t)(k0 + ty + j * 8) * N + n0 + tx];
    __syncthreads();
#pragma unroll
    for (int j = 0; j < 4; ++j)
        Wt[(size_t)(n0 + ty + j * 8) * K + k0 + tx] = (bf16)t[tx][ty + j * 8];
}

// ---------------------------------------------------------------------------
// C[M][N](bf16) = A[M][K](bf16) @ Bt[N][K]^T + bias, optional ReLU.
// 128x128 tile, BK=32, 4 waves (2x2), each wave 64x64 via 4x4 mfma 16x16x32.
template<bool RELU>
__global__ __launch_bounds__(256, 2)
void gemm_bf16(const bf16* __restrict__ A, const bf16* __restrict__ Bt,
               const float* __restrict__ bias, bf16* __restrict__ C,
               int M, int N, int K) {
    __shared__ alignas(16) bf16 Alds[128 * 32];
    __shared__ alignas(16) bf16 Blds[128 * 32];
    const int tid = threadIdx.x;
    const int wave = tid >> 6, lane = tid & 63;
    const int wr = wave >> 1, wc = wave & 1;
    const int m0 = blockIdx.y * 128, n0 = blockIdx.x * 128;
    const int lr = lane & 15;          // A/B frag row (lane%16)
    const int lg = lane >> 4;          // k-group
    const int lk = lg * 8;             // k offset within 32

    const int srow = lane >> 2;        // staging: 0..15
    const int scol = (lane & 3) * 8;   // staging col (elems)

    f32x4 acc[4][4] = {};

    for (int k0 = 0; k0 < K; k0 += 32) {
#pragma unroll
        for (int j = 0; j < 2; ++j) {
            int row = wave * 32 + j * 16 + srow;
            async_load16(A + (size_t)(m0 + row) * K + k0 + scol,
                         Alds + (wave * 32 + j * 16) * 32);
            async_load16(Bt + (size_t)(n0 + row) * K + k0 + scol,
                         Blds + (wave * 32 + j * 16) * 32);
        }
        __syncthreads();

        bf16x8 af[4], bfv[4];
#pragma unroll
        for (int i = 0; i < 4; ++i) {
            af[i]  = *(const bf16x8*)&Alds[(wr * 64 + i * 16 + lr) * 32 + lk];
            bfv[i] = *(const bf16x8*)&Blds[(wc * 64 + i * 16 + lr) * 32 + lk];
        }
#pragma unroll
        for (int mi = 0; mi < 4; ++mi)
#pragma unroll
            for (int ni = 0; ni < 4; ++ni)
                acc[mi][ni] = __builtin_amdgcn_mfma_f32_16x16x32_bf16(
                    af[mi], bfv[ni], acc[mi][ni], 0, 0, 0);
        __syncthreads();
    }

#pragma unroll
    for (int ni = 0; ni < 4; ++ni) {
        int n = n0 + wc * 64 + ni * 16 + lr;
        float bn = bias[n];
#pragma unroll
        for (int mi = 0; mi < 4; ++mi) {
#pragma unroll
            for (int r = 0; r < 4; ++r) {
                int m = m0 + wr * 64 + mi * 16 + lg * 4 + r;
                float v = acc[mi][ni][r] + bn;
                if (RELU) v = v > 0.f ? v : 0.f;
                C[(size_t)m * N + n] = (bf16)v;
            }
        }
    }
}

// ---------------------------------------------------------------------------
// Flash attention. One block = (b, h, 64 q-rows); 4 waves x 16 q-rows.
// scores = (Q K^T) / 32 (reference scales by sqrt(D)=32, not sqrt(HD)).
// mask: kk < lk && q < lq && (!CAUSAL || kk <= q); fully-masked row -> 0.
template<bool CAUSAL>
__global__ __launch_bounds__(256, 2)
void attn_flash(const bf16* __restrict__ Qp, int qs,
                const bf16* __restrict__ Kp, int ks,
                const bf16* __restrict__ Vp, int vs,
                const int* __restrict__ Lq, const int* __restrict__ Lk,
                bf16* __restrict__ Op) {
    __shared__ alignas(16) bf16 Klds[32 * 64];
    __shared__ alignas(16) bf16 Vt[64 * 32];
    __shared__ alignas(16) bf16 Plds[4][16 * 32];

    const int tid = threadIdx.x;
    const int wave = tid >> 6, lane = tid & 63;
    const int qt = blockIdx.x, h = blockIdx.y, b = blockIdx.z;
    const int q0 = qt * 64;
    const int lq = Lq[b], lk = Lk[b];
    const int lr = lane & 15, lg = lane >> 4;

    // Q fragments (held in regs for the whole KV loop)
    bf16x8 aq[2];
    {
        const bf16* qrow = Qp + (size_t)(b * S_LEN + q0 + wave * 16 + lr) * qs + h * HDIM;
        aq[0] = *(const bf16x8*)(qrow + 0 + lg * 8);
        aq[1] = *(const bf16x8*)(qrow + 32 + lg * 8);
    }

    f32x4 o[4] = {};
    float m_run[4], l_run[4];
#pragma unroll
    for (int r = 0; r < 4; ++r) { m_run[r] = -INFINITY; l_run[r] = 0.f; }

    int kv_end = CAUSAL ? (q0 + 64) : S_LEN;
    int lk_cap = (lk + 31) & ~31;
    if (kv_end > lk_cap) kv_end = lk_cap;

    const int srow = tid >> 3;           // 0..31 (kv row in tile)
    const int schunk = (tid & 7) * 8;    // 8-elem chunk within 64

    for (int kk0 = 0; kk0 < kv_end; kk0 += 32) {
        // stage K tile [32][64] and V tile transposed [64][32]
        {
            const bf16* ksrc = Kp + (size_t)(b * S_LEN + kk0 + srow) * ks + h * HDIM + schunk;
            *(u32x4*)&Klds[srow * 64 + schunk] = *(const u32x4*)ksrc;
            bf16x8 vv = *(const bf16x8*)(Vp + (size_t)(b * S_LEN + kk0 + srow) * vs + h * HDIM + schunk);
#pragma unroll
            for (int e = 0; e < 8; ++e)
                Vt[(schunk + e) * 32 + srow] = vv[e];
        }
        __syncthreads();

        // S = Q K^T  (two 16-wide kk tiles, K=64 contraction via 2 mfma)
        f32x4 sa[2];
#pragma unroll
        for (int kt = 0; kt < 2; ++kt) {
            f32x4 z = {};
            bf16x8 bk0 = *(const bf16x8*)&Klds[(kt * 16 + lr) * 64 + 0 + lg * 8];
            bf16x8 bk1 = *(const bf16x8*)&Klds[(kt * 16 + lr) * 64 + 32 + lg * 8];
            z = __builtin_amdgcn_mfma_f32_16x16x32_bf16(aq[0], bk0, z, 0, 0, 0);
            z = __builtin_amdgcn_mfma_f32_16x16x32_bf16(aq[1], bk1, z, 0, 0, 0);
            sa[kt] = z;
        }

        // scale + mask + online softmax
        float p[2][4], mtile[4];
#pragma unroll
        for (int r = 0; r < 4; ++r) {
            int q = q0 + wave * 16 + lg * 4 + r;
            float best = -INFINITY;
#pragma unroll
            for (int kt = 0; kt < 2; ++kt) {
                int kk = kk0 + kt * 16 + lr;
                float s = sa[kt][r] * 0.03125f;
                bool ok = (q < lq) && (kk < lk) && (!CAUSAL || kk <= q);
                s = ok ? s : -INFINITY;
                p[kt][r] = s;
                best = fmaxf(best, s);
            }
#pragma unroll
            for (int msk = 1; msk < 16; msk <<= 1)
                best = fmaxf(best, __shfl_xor(best, msk));
            mtile[r] = best;
        }
#pragma unroll
        for (int r = 0; r < 4; ++r) {
            float mn = fmaxf(m_run[r], mtile[r]);
            float alpha = (m_run[r] == -INFINITY) ? 0.0f : __expf(m_run[r] - mn);
            float rs = 0.f;
#pragma unroll
            for (int kt = 0; kt < 2; ++kt) {
                float s = p[kt][r];
                float e = (s == -INFINITY) ? 0.f : __expf(s - mn);
                p[kt][r] = e;
                rs += e;
            }
#pragma unroll
            for (int msk = 1; msk < 16; msk <<= 1)
                rs += __shfl_xor(rs, msk);
            l_run[r] = l_run[r] * alpha + rs;
            m_run[r] = mn;
#pragma unroll
            for (int dt = 0; dt < 4; ++dt) o[dt][r] *= alpha;
        }

        // P (D-layout) -> LDS -> A-layout bf16 frag; per-wave buffer, in-order DS
#pragma unroll
        for (int kt = 0; kt < 2; ++kt)
#pragma unroll
            for (int r = 0; r < 4; ++r)
                Plds[wave][(lg * 4 + r) * 32 + kt * 16 + lr] = (bf16)p[kt][r];
        bf16x8 pa = *(const bf16x8*)&Plds[wave][lr * 32 + lg * 8];

        // O += P @ V
#pragma unroll
        for (int dt = 0; dt < 4; ++dt) {
            bf16x8 bv = *(const bf16x8*)&Vt[(dt * 16 + lr) * 32 + lg * 8];
            o[dt] = __builtin_amdgcn_mfma_f32_16x16x32_bf16(pa, bv, o[dt], 0, 0, 0);
        }
        __syncthreads();
    }

    // epilogue: divide by row-sum (0 if fully masked), write [b,s, h*64+d]
#pragma unroll
    for (int dt = 0; dt < 4; ++dt) {
#pragma unroll
        for (int r = 0; r < 4; ++r) {
            int q = q0 + wave * 16 + lg * 4 + r;
            float denom = l_run[r];
            float val = denom > 0.f ? o[dt][r] / denom : 0.f;
            Op[(size_t)(b * S_LEN + q) * DMODEL + h * HDIM + dt * 16 + lr] = (bf16)val;
        }
    }
}

// ---------------------------------------------------------------------------
// y = LayerNorm(x_bf16 + rc_f32) * g + b ; writes f32 (optional) + bf16 (optional)
__global__ __launch_bounds__(256)
void ln_kernel(const bf16* __restrict__ x, const float* __restrict__ rc,
               const float* __restrict__ g, const float* __restrict__ beta,
               float* __restrict__ yf, bf16* __restrict__ yb) {
    const int row = blockIdx.x;
    const int tid = threadIdx.x;
    const int wave = tid >> 6, lane = tid & 63;
    const bf16* xr = x + (size_t)row * DMODEL;
    const float* rr = rc + (size_t)row * DMODEL;

    float v[4];
    {
        bf16x4 xv = *(const bf16x4*)(xr + tid * 4);
        f32x4 rv = *(const f32x4*)(rr + tid * 4);
#pragma unroll
        for (int i = 0; i < 4; ++i) v[i] = (float)xv[i] + rv[i];
    }
    float s = v[0] + v[1] + v[2] + v[3];
    float s2 = v[0] * v[0] + v[1] * v[1] + v[2] * v[2] + v[3] * v[3];
#pragma unroll
    for (int msk = 1; msk < 64; msk <<= 1) {
        s += __shfl_xor(s, msk);
        s2 += __shfl_xor(s2, msk);
    }
    __shared__ float red[8];
    if (lane == 0) { red[wave] = s; red[4 + wave] = s2; }
    __syncthreads();
    float ts = red[0] + red[1] + red[2] + red[3];
    float ts2 = red[4] + red[5] + red[6] + red[7];
    float mean = ts * (1.f / DMODEL);
    float var = ts2 * (1.f / DMODEL) - mean * mean;
    float inv = rsqrtf(var + 1e-5f);
#pragma unroll
    for (int i = 0; i < 4; ++i) {
        int c = tid * 4 + i;
        float yv = (v[i] - mean) * inv * g[c] + beta[c];
        if (yf) yf[(size_t)row * DMODEL + c] = yv;
        if (yb) yb[(size_t)row * DMODEL + c] = (bf16)yv;
    }
}

// ---------------------------------------------------------------------------
extern "C" void kernel_launch(void* const* d_in, const int* in_sizes, int n_in,
                              void* d_out, int out_size, void* d_ws, size_t ws_size,
                              hipStream_t stream) {
    const float* en     = (const float*)d_in[0];
    const float* fr     = (const float*)d_in[1];
    const float* W_attn = (const float*)d_in[2];
    const float* b_attn = (const float*)d_in[3];
    const float* W_Q    = (const float*)d_in[4];
    const float* b_Q    = (const float*)d_in[5];
    const float* W_KV   = (const float*)d_in[6];
    const float* b_KV   = (const float*)d_in[7];
    const float* ln_g   = (const float*)d_in[8];
    const float* ln_b   = (const float*)d_in[9];
    const float* W1     = (const float*)d_in[10];
    const float* b1     = (const float*)d_in[11];
    const float* W2     = (const float*)d_in[12];
    const float* b2     = (const float*)d_in[13];
    const int* l_en     = (const int*)d_in[14];
    const int* l_fr     = (const int*)d_in[15];
    float* out = (float*)d_out;

    char* ws = (char*)d_ws;
    const size_t MB = (size_t)1 << 20;
    bf16* Wt_attn = (bf16*)(ws + 0);        //  6 MB  [1024x3072]^T
    bf16* Wt_Q    = (bf16*)(ws + 6 * MB);   //  2 MB
    bf16* Wt_KV   = (bf16*)(ws + 8 * MB);   //  4 MB
    bf16* Wt_1    = (bf16*)(ws + 12 * MB);  //  8 MB
    bf16* Wt_2    = (bf16*)(ws + 20 * MB);  //  8 MB
    bf16* fr_bf   = (bf16*)(ws + 28 * MB);  //  8 MB
    bf16* en_bf   = (bf16*)(ws + 36 * MB);  //  8 MB
    bf16* bigA    = (bf16*)(ws + 44 * MB);  // 32 MB: qkv | (qc,kvc) | h
    bf16* xbuf    = (bf16*)(ws + 76 * MB);  //  8 MB: x1 | x2 | h2
    float* fr2    = (float*)(ws + 84 * MB); // 16 MB
    float* fr3    = (float*)(ws + 100 * MB);// 16 MB
    bf16* fbx     = (bf16*)(ws + 116 * MB); //  8 MB: fr2_bf then fr3_bf
    // total 124 MB

    dim3 blk(256);

    // converts + weight transposes
    cvt_f32_bf16<<<dim3(4096), blk, 0, stream>>>(fr, fr_bf, MROWS * DMODEL / 4);
    cvt_f32_bf16<<<dim3(4096), blk, 0, stream>>>(en, en_bf, MROWS * DMODEL / 4);
    wconv<<<dim3(96, 32), blk, 0, stream>>>(W_attn, Wt_attn, 1024, 3072);
    wconv<<<dim3(32, 32), blk, 0, stream>>>(W_Q, Wt_Q, 1024, 1024);
    wconv<<<dim3(64, 32), blk, 0, stream>>>(W_KV, Wt_KV, 1024, 2048);
    wconv<<<dim3(128, 32), blk, 0, stream>>>(W1, Wt_1, 1024, 4096);
    wconv<<<dim3(32, 128), blk, 0, stream>>>(W2, Wt_2, 4096, 1024);

    // --- self attention ---
    bf16* qkv = bigA;  // [4096][3072]
    gemm_bf16<false><<<dim3(24, 32), blk, 0, stream>>>(fr_bf, Wt_attn, b_attn, qkv, MROWS, 3072, 1024);
    attn_flash<true><<<dim3(16, NHEAD, BATCH), blk, 0, stream>>>(
        qkv, 3072, qkv + 1024, 3072, qkv + 2048, 3072, l_fr, l_fr, xbuf);
    ln_kernel<<<dim3(4096), blk, 0, stream>>>(xbuf, fr, ln_g, ln_b, fr2, fbx);

    // --- cross attention ---
    bf16* qc  = bigA;                                   // [4096][1024]
    bf16* kvc = (bf16*)((char*)bigA + 8 * MB);          // [4096][2048]
    gemm_bf16<false><<<dim3(8, 32), blk, 0, stream>>>(fbx, Wt_Q, b_Q, qc, MROWS, 1024, 1024);
    gemm_bf16<false><<<dim3(16, 32), blk, 0, stream>>>(en_bf, Wt_KV, b_KV, kvc, MROWS, 2048, 1024);
    attn_flash<false><<<dim3(16, NHEAD, BATCH), blk, 0, stream>>>(
        qc, 1024, kvc, 2048, kvc + 1024, 2048, l_fr, l_en, xbuf);
    ln_kernel<<<dim3(4096), blk, 0, stream>>>(xbuf, fr2, ln_g, ln_b, fr3, fbx);

    // --- FFN ---
    bf16* h = bigA;  // [4096][4096]
    gemm_bf16<true><<<dim3(32, 32), blk, 0, stream>>>(fbx, Wt_1, b1, h, MROWS, 4096, 1024);
    gemm_bf16<true><<<dim3(8, 32), blk, 0, stream>>>(h, Wt_2, b2, xbuf, MROWS, 1024, 4096);
    ln_kernel<<<dim3(4096), blk, 0, stream>>>(xbuf, fr3, ln_g, ln_b, out, nullptr);
}

// Round 2
// 371.195 us; speedup vs baseline: 1.1252x; 1.1252x over previous
//
#include <hip/hip_runtime.h>
#include <hip/hip_bf16.h>
#include <cstdint>
#include <cstddef>

#define S_LEN  1024
#define DMODEL 1024
#define NHEAD  16
#define HDIM   64
#define BATCH  4
#define MROWS  (BATCH * S_LEN)   // 4096

typedef __bf16 bf16;
typedef __attribute__((ext_vector_type(8))) __bf16 bf16x8;
typedef __attribute__((ext_vector_type(4))) __bf16 bf16x4;
typedef __attribute__((ext_vector_type(4))) float f32x4;
typedef __attribute__((ext_vector_type(4))) unsigned int u32x4;

// ---------------------------------------------------------------------------
// async global->LDS, 16B per lane. LDS dest must be wave-uniform base.
__device__ __forceinline__ void async_load16(const void* g, void* l) {
    __builtin_amdgcn_global_load_lds(
        (const __attribute__((address_space(1))) unsigned int*)g,
        (__attribute__((address_space(3))) unsigned int*)l,
        16, 0, 0);
}

// ---------------------------------------------------------------------------
// f32 -> bf16 elementwise convert (vectorized x4)
__global__ __launch_bounds__(256)
void cvt_f32_bf16(const float* __restrict__ in, bf16* __restrict__ out, int n4) {
    int i = blockIdx.x * 256 + threadIdx.x;
    if (i >= n4) return;
    f32x4 v = ((const f32x4*)in)[i];
    bf16x4 o;
#pragma unroll
    for (int e = 0; e < 4; ++e) o[e] = (bf16)v[e];
    ((bf16x4*)out)[i] = o;
}

// ---------------------------------------------------------------------------
// W[K][N] f32  ->  Wt[N][K] bf16   (LDS-tiled transpose, 32x32 tiles)
__global__ __launch_bounds__(256)
void wconv(const float* __restrict__ W, bf16* __restrict__ Wt, int K, int N) {
    __shared__ float t[32][33];
    int n0 = blockIdx.x * 32, k0 = blockIdx.y * 32;
    int tx = threadIdx.x & 31, ty = threadIdx.x >> 5;  // 32 x 8
#pragma unroll
    for (int j = 0; j < 4; ++j)
        t[ty + j * 8][tx] = W[(size_t)(k0 + ty + j * 8) * N + n0 + tx];
    __syncthreads();
#pragma unroll
    for (int j = 0; j < 4; ++j)
        Wt[(size_t)(n0 + ty + j * 8) * K + k0 + tx] = (bf16)t[tx][ty + j * 8];
}

// ---------------------------------------------------------------------------
// C[M][N](bf16) = A[M][K](bf16) @ Bt[N][K]^T + bias, optional ReLU.
// 128x128 tile, BK=32, 4 waves (2x2), each wave 64x64 via 4x4 mfma 16x16x32.
template<bool RELU>
__global__ __launch_bounds__(256, 2)
void gemm_bf16(const bf16* __restrict__ A, const bf16* __restrict__ Bt,
               const float* __restrict__ bias, bf16* __restrict__ C,
               int M, int N, int K) {
    __shared__ alignas(16) bf16 Alds[128 * 32];
    __shared__ alignas(16) bf16 Blds[128 * 32];
    const int tid = threadIdx.x;
    const int wave = tid >> 6, lane = tid & 63;
    const int wr = wave >> 1, wc = wave & 1;
    const int m0 = blockIdx.y * 128, n0 = blockIdx.x * 128;
    const int lr = lane & 15;          // A/B frag row (lane%16)
    const int lg = lane >> 4;          // k-group
    const int lk = lg * 8;             // k offset within 32

    const int srow = lane >> 2;        // staging: 0..15
    const int scol = (lane & 3) * 8;   // staging col (elems)

    f32x4 acc[4][4] = {};

    for (int k0 = 0; k0 < K; k0 += 32) {
#pragma unroll
        for (int j = 0; j < 2; ++j) {
            int row = wave * 32 + j * 16 + srow;
            async_load16(A + (size_t)(m0 + row) * K + k0 + scol,
                         Alds + (wave * 32 + j * 16) * 32);
            async_load16(Bt + (size_t)(n0 + row) * K + k0 + scol,
                         Blds + (wave * 32 + j * 16) * 32);
        }
        __syncthreads();

        bf16x8 af[4], bfv[4];
#pragma unroll
        for (int i = 0; i < 4; ++i) {
            af[i]  = *(const bf16x8*)&Alds[(wr * 64 + i * 16 + lr) * 32 + lk];
            bfv[i] = *(const bf16x8*)&Blds[(wc * 64 + i * 16 + lr) * 32 + lk];
        }
#pragma unroll
        for (int mi = 0; mi < 4; ++mi)
#pragma unroll
            for (int ni = 0; ni < 4; ++ni)
                acc[mi][ni] = __builtin_amdgcn_mfma_f32_16x16x32_bf16(
                    af[mi], bfv[ni], acc[mi][ni], 0, 0, 0);
        __syncthreads();
    }

#pragma unroll
    for (int ni = 0; ni < 4; ++ni) {
        int n = n0 + wc * 64 + ni * 16 + lr;
        float bn = bias[n];
#pragma unroll
        for (int mi = 0; mi < 4; ++mi) {
#pragma unroll
            for (int r = 0; r < 4; ++r) {
                int m = m0 + wr * 64 + mi * 16 + lg * 4 + r;
                float v = acc[mi][ni][r] + bn;
                if (RELU) v = v > 0.f ? v : 0.f;
                C[(size_t)m * N + n] = (bf16)v;
            }
        }
    }
}

// ---------------------------------------------------------------------------
// Flash attention, KVBLK=64, XOR-swizzled LDS (conflict-free b128 reads).
// One block = (b, h, 64 q-rows); 4 waves x 16 q-rows.
// scores = (Q K^T) / 32 (reference scales by sqrt(D)=32, not sqrt(HD)).
// mask: kk < lk && q < lq && (!CAUSAL || kk <= q); fully-masked row -> 0.
template<bool CAUSAL>
__global__ __launch_bounds__(256, 4)
void attn_flash(const bf16* __restrict__ Qp, int qs,
                const bf16* __restrict__ Kp, int ks,
                const bf16* __restrict__ Vp, int vs,
                const int* __restrict__ Lq, const int* __restrict__ Lk,
                bf16* __restrict__ Op) {
    // K: [64 kk][64 d], row byte ^= ((kk&7)<<4); staged linear w/ pre-swizzled src
    // Vt: [64 d][64 k], row byte ^= ((d&7)<<4); reg-transposed
    // Plds: per-wave [16 q][64 kk], row byte ^= ((q&7)<<4)
    __shared__ alignas(16) bf16 Klds[64 * 64];
    __shared__ alignas(16) bf16 Vt[64 * 64];
    __shared__ alignas(16) bf16 Plds[4][16 * 64];

    const int tid = threadIdx.x;
    const int wave = tid >> 6, lane = tid & 63;
    const int qt = blockIdx.x, h = blockIdx.y, b = blockIdx.z;
    const int q0 = qt * 64;
    const int lq = Lq[b], lk = Lk[b];
    const int lr = lane & 15, lg = lane >> 4;

    char* KldsB = (char*)Klds;
    char* VtB = (char*)Vt;
    char* PldsB = (char*)&Plds[wave][0];

    // Q fragments (regs for whole KV loop): A-frag lane lr = q-row, lg*8+e = d
    bf16x8 aq[2];
    {
        const bf16* qrow = Qp + (size_t)(b * S_LEN + q0 + wave * 16 + lr) * qs + h * HDIM;
        aq[0] = *(const bf16x8*)(qrow + 0 + lg * 8);
        aq[1] = *(const bf16x8*)(qrow + 32 + lg * 8);
    }

    f32x4 o[4] = {};
    float m_run[4], l_run[4];
#pragma unroll
    for (int r = 0; r < 4; ++r) { m_run[r] = -INFINITY; l_run[r] = 0.f; }

    int kv_end = CAUSAL ? (q0 + 64) : S_LEN;
    int lk_cap = (lk + 63) & ~63;
    if (kv_end > lk_cap) kv_end = lk_cap;

    // V stage mapping: lane -> k, wave -> 16-d chunk
    const int vk = lane;
    const int vd0 = wave * 16;

    for (int kk0 = 0; kk0 < kv_end; kk0 += 64) {
        // --- stage K via global_load_lds: linear LDS dest, pre-swizzled source
#pragma unroll
        for (int c = 0; c < 2; ++c) {
            int rloc = c * 8 + (lane >> 3);               // row within wave's 16
            int row = wave * 16 + rloc;
            int chunk = (lane & 7) ^ (rloc & 7);          // row&7 == rloc&7
            async_load16(Kp + (size_t)(b * S_LEN + kk0 + row) * ks + h * HDIM + chunk * 8,
                         KldsB + (size_t)(wave * 16 + c * 8) * 128);
        }
        // --- stage V transposed (reg): thread (wave,lane) reads V[kk0+vk][vd0..+15]
        {
            const bf16* vsrc = Vp + (size_t)(b * S_LEN + kk0 + vk) * vs + h * HDIM + vd0;
            bf16x8 v0 = *(const bf16x8*)vsrc;
            bf16x8 v1 = *(const bf16x8*)(vsrc + 8);
#pragma unroll
            for (int e = 0; e < 8; ++e) {
                int d0 = vd0 + e, d1 = vd0 + 8 + e;
                *(bf16*)(VtB + (((size_t)d0 * 128 + vk * 2) ^ ((d0 & 7) << 4))) = v0[e];
                *(bf16*)(VtB + (((size_t)d1 * 128 + vk * 2) ^ ((d1 & 7) << 4))) = v1[e];
            }
        }
        __syncthreads();

        // --- S = Q K^T : 4 kt tiles of 16 kk, contraction d=64 via 2 mfma
        f32x4 sa[4];
#pragma unroll
        for (int kt = 0; kt < 4; ++kt) {
            int row = kt * 16 + lr;
            f32x4 z = {};
#pragma unroll
            for (int ds_ = 0; ds_ < 2; ++ds_) {
                bf16x8 bk = *(const bf16x8*)(KldsB +
                    (((size_t)row * 128 + ds_ * 64 + lg * 16) ^ ((row & 7) << 4)));
                z = __builtin_amdgcn_mfma_f32_16x16x32_bf16(aq[ds_], bk, z, 0, 0, 0);
            }
            sa[kt] = z;
        }

        // --- scale + mask + online softmax (q = q0 + wave*16 + lg*4 + r)
        float p[4][4];
#pragma unroll
        for (int r = 0; r < 4; ++r) {
            int q = q0 + wave * 16 + lg * 4 + r;
            float best = -INFINITY;
#pragma unroll
            for (int kt = 0; kt < 4; ++kt) {
                int kk = kk0 + kt * 16 + lr;
                float s = sa[kt][r] * 0.03125f;
                bool ok = (q < lq) && (kk < lk) && (!CAUSAL || kk <= q);
                s = ok ? s : -INFINITY;
                p[kt][r] = s;
                best = fmaxf(best, s);
            }
#pragma unroll
            for (int msk = 1; msk < 16; msk <<= 1)
                best = fmaxf(best, __shfl_xor(best, msk));
            float mn = fmaxf(m_run[r], best);
            float alpha = (m_run[r] == -INFINITY) ? 0.0f : __expf(m_run[r] - mn);
            float rs = 0.f;
#pragma unroll
            for (int kt = 0; kt < 4; ++kt) {
                float s = p[kt][r];
                float e = (s == -INFINITY) ? 0.f : __expf(s - mn);
                p[kt][r] = e;
                rs += e;
            }
#pragma unroll
            for (int msk = 1; msk < 16; msk <<= 1)
                rs += __shfl_xor(rs, msk);
            l_run[r] = l_run[r] * alpha + rs;
            m_run[r] = mn;
#pragma unroll
            for (int dt = 0; dt < 4; ++dt) o[dt][r] *= alpha;
        }

        // --- P (D-layout) -> per-wave swizzled LDS -> A-frag
#pragma unroll
        for (int kt = 0; kt < 4; ++kt)
#pragma unroll
            for (int r = 0; r < 4; ++r) {
                int ql = lg * 4 + r, kkl = kt * 16 + lr;
                *(bf16*)(PldsB + (((size_t)ql * 128 + kkl * 2) ^ ((ql & 7) << 4))) =
                    (bf16)p[kt][r];
            }
        bf16x8 pa[2];
#pragma unroll
        for (int ksl = 0; ksl < 2; ++ksl)
            pa[ksl] = *(const bf16x8*)(PldsB +
                (((size_t)lr * 128 + ksl * 64 + lg * 16) ^ ((lr & 7) << 4)));

        // --- O += P @ V  (B from Vt[d][k], contraction k=64 via 2 mfma)
#pragma unroll
        for (int dt = 0; dt < 4; ++dt) {
            int row = dt * 16 + lr;
#pragma unroll
            for (int ksl = 0; ksl < 2; ++ksl) {
                bf16x8 bv = *(const bf16x8*)(VtB +
                    (((size_t)row * 128 + ksl * 64 + lg * 16) ^ ((row & 7) << 4)));
                o[dt] = __builtin_amdgcn_mfma_f32_16x16x32_bf16(pa[ksl], bv, o[dt], 0, 0, 0);
            }
        }
        __syncthreads();
    }

    // epilogue: divide by row-sum (0 if fully masked), write [b,s, h*64+d]
#pragma unroll
    for (int dt = 0; dt < 4; ++dt) {
#pragma unroll
        for (int r = 0; r < 4; ++r) {
            int q = q0 + wave * 16 + lg * 4 + r;
            float denom = l_run[r];
            float val = denom > 0.f ? o[dt][r] / denom : 0.f;
            Op[(size_t)(b * S_LEN + q) * DMODEL + h * HDIM + dt * 16 + lr] = (bf16)val;
        }
    }
}

// ---------------------------------------------------------------------------
// y = LayerNorm(x_bf16 + rc_f32) * g + b ; writes f32 (optional) + bf16 (optional)
__global__ __launch_bounds__(256)
void ln_kernel(const bf16* __restrict__ x, const float* __restrict__ rc,
               const float* __restrict__ g, const float* __restrict__ beta,
               float* __restrict__ yf, bf16* __restrict__ yb) {
    const int row = blockIdx.x;
    const int tid = threadIdx.x;
    const int wave = tid >> 6, lane = tid & 63;
    const bf16* xr = x + (size_t)row * DMODEL;
    const float* rr = rc + (size_t)row * DMODEL;

    float v[4];
    {
        bf16x4 xv = *(const bf16x4*)(xr + tid * 4);
        f32x4 rv = *(const f32x4*)(rr + tid * 4);
#pragma unroll
        for (int i = 0; i < 4; ++i) v[i] = (float)xv[i] + rv[i];
    }
    float s = v[0] + v[1] + v[2] + v[3];
    float s2 = v[0] * v[0] + v[1] * v[1] + v[2] * v[2] + v[3] * v[3];
#pragma unroll
    for (int msk = 1; msk < 64; msk <<= 1) {
        s += __shfl_xor(s, msk);
        s2 += __shfl_xor(s2, msk);
    }
    __shared__ float red[8];
    if (lane == 0) { red[wave] = s; red[4 + wave] = s2; }
    __syncthreads();
    float ts = red[0] + red[1] + red[2] + red[3];
    float ts2 = red[4] + red[5] + red[6] + red[7];
    float mean = ts * (1.f / DMODEL);
    float var = ts2 * (1.f / DMODEL) - mean * mean;
    float inv = rsqrtf(var + 1e-5f);
#pragma unroll
    for (int i = 0; i < 4; ++i) {
        int c = tid * 4 + i;
        float yv = (v[i] - mean) * inv * g[c] + beta[c];
        if (yf) yf[(size_t)row * DMODEL + c] = yv;
        if (yb) yb[(size_t)row * DMODEL + c] = (bf16)yv;
    }
}

// ---------------------------------------------------------------------------
extern "C" void kernel_launch(void* const* d_in, const int* in_sizes, int n_in,
                              void* d_out, int out_size, void* d_ws, size_t ws_size,
                              hipStream_t stream) {
    const float* en     = (const float*)d_in[0];
    const float* fr     = (const float*)d_in[1];
    const float* W_attn = (const float*)d_in[2];
    const float* b_attn = (const float*)d_in[3];
    const float* W_Q    = (const float*)d_in[4];
    const float* b_Q    = (const float*)d_in[5];
    const float* W_KV   = (const float*)d_in[6];
    const float* b_KV   = (const float*)d_in[7];
    const float* ln_g   = (const float*)d_in[8];
    const float* ln_b   = (const float*)d_in[9];
    const float* W1     = (const float*)d_in[10];
    const float* b1     = (const float*)d_in[11];
    const float* W2     = (const float*)d_in[12];
    const float* b2     = (const float*)d_in[13];
    const int* l_en     = (const int*)d_in[14];
    const int* l_fr     = (const int*)d_in[15];
    float* out = (float*)d_out;

    char* ws = (char*)d_ws;
    const size_t MB = (size_t)1 << 20;
    bf16* Wt_attn = (bf16*)(ws + 0);        //  6 MB  [1024x3072]^T
    bf16* Wt_Q    = (bf16*)(ws + 6 * MB);   //  2 MB
    bf16* Wt_KV   = (bf16*)(ws + 8 * MB);   //  4 MB
    bf16* Wt_1    = (bf16*)(ws + 12 * MB);  //  8 MB
    bf16* Wt_2    = (bf16*)(ws + 20 * MB);  //  8 MB
    bf16* fr_bf   = (bf16*)(ws + 28 * MB);  //  8 MB
    bf16* en_bf   = (bf16*)(ws + 36 * MB);  //  8 MB
    bf16* bigA    = (bf16*)(ws + 44 * MB);  // 32 MB: qkv | (qc,kvc) | h
    bf16* xbuf    = (bf16*)(ws + 76 * MB);  //  8 MB: x1 | x2 | h2
    float* fr2    = (float*)(ws + 84 * MB); // 16 MB
    float* fr3    = (float*)(ws + 100 * MB);// 16 MB
    bf16* fbx     = (bf16*)(ws + 116 * MB); //  8 MB: fr2_bf then fr3_bf
    // total 124 MB

    dim3 blk(256);

    // converts + weight transposes
    cvt_f32_bf16<<<dim3(4096), blk, 0, stream>>>(fr, fr_bf, MROWS * DMODEL / 4);
    cvt_f32_bf16<<<dim3(4096), blk, 0, stream>>>(en, en_bf, MROWS * DMODEL / 4);
    wconv<<<dim3(96, 32), blk, 0, stream>>>(W_attn, Wt_attn, 1024, 3072);
    wconv<<<dim3(32, 32), blk, 0, stream>>>(W_Q, Wt_Q, 1024, 1024);
    wconv<<<dim3(64, 32), blk, 0, stream>>>(W_KV, Wt_KV, 1024, 2048);
    wconv<<<dim3(128, 32), blk, 0, stream>>>(W1, Wt_1, 1024, 4096);
    wconv<<<dim3(32, 128), blk, 0, stream>>>(W2, Wt_2, 4096, 1024);

    // --- self attention ---
    bf16* qkv = bigA;  // [4096][3072]
    gemm_bf16<false><<<dim3(24, 32), blk, 0, stream>>>(fr_bf, Wt_attn, b_attn, qkv, MROWS, 3072, 1024);
    attn_flash<true><<<dim3(16, NHEAD, BATCH), blk, 0, stream>>>(
        qkv, 3072, qkv + 1024, 3072, qkv + 2048, 3072, l_fr, l_fr, xbuf);
    ln_kernel<<<dim3(4096), blk, 0, stream>>>(xbuf, fr, ln_g, ln_b, fr2, fbx);

    // --- cross attention ---
    bf16* qc  = bigA;                                   // [4096][1024]
    bf16* kvc = (bf16*)((char*)bigA + 8 * MB);          // [4096][2048]
    gemm_bf16<false><<<dim3(8, 32), blk, 0, stream>>>(fbx, Wt_Q, b_Q, qc, MROWS, 1024, 1024);
    gemm_bf16<false><<<dim3(16, 32), blk, 0, stream>>>(en_bf, Wt_KV, b_KV, kvc, MROWS, 2048, 1024);
    attn_flash<false><<<dim3(16, NHEAD, BATCH), blk, 0, stream>>>(
        qc, 1024, kvc, 2048, kvc + 1024, 2048, l_fr, l_en, xbuf);
    ln_kernel<<<dim3(4096), blk, 0, stream>>>(xbuf, fr2, ln_g, ln_b, fr3, fbx);

    // --- FFN ---
    bf16* h = bigA;  // [4096][4096]
    gemm_bf16<true><<<dim3(32, 32), blk, 0, stream>>>(fbx, Wt_1, b1, h, MROWS, 4096, 1024);
    gemm_bf16<true><<<dim3(8, 32), blk, 0, stream>>>(h, Wt_2, b2, xbuf, MROWS, 1024, 4096);
    ln_kernel<<<dim3(4096), blk, 0, stream>>>(xbuf, fr3, ln_g, ln_b, out, nullptr);
}

// Round 3
// 352.753 us; speedup vs baseline: 1.1840x; 1.0523x over previous
//
#include <hip/hip_runtime.h>
#include <hip/hip_bf16.h>
#include <cstdint>
#include <cstddef>

#define S_LEN  1024
#define DMODEL 1024
#define NHEAD  16
#define HDIM   64
#define BATCH  4
#define MROWS  (BATCH * S_LEN)   // 4096

typedef __bf16 bf16;
typedef __attribute__((ext_vector_type(8))) __bf16 bf16x8;
typedef __attribute__((ext_vector_type(4))) __bf16 bf16x4;
typedef __attribute__((ext_vector_type(4))) float f32x4;
typedef __attribute__((ext_vector_type(4))) unsigned int u32x4;

// ---------------------------------------------------------------------------
// async global->LDS, 16B per lane. LDS dest must be wave-uniform base.
__device__ __forceinline__ void async_load16(const void* g, void* l) {
    __builtin_amdgcn_global_load_lds(
        (const __attribute__((address_space(1))) unsigned int*)g,
        (__attribute__((address_space(3))) unsigned int*)l,
        16, 0, 0);
}

// ---------------------------------------------------------------------------
// f32 -> bf16 elementwise convert (vectorized x4)
__global__ __launch_bounds__(256)
void cvt_f32_bf16(const float* __restrict__ in, bf16* __restrict__ out, int n4) {
    int i = blockIdx.x * 256 + threadIdx.x;
    if (i >= n4) return;
    f32x4 v = ((const f32x4*)in)[i];
    bf16x4 o;
#pragma unroll
    for (int e = 0; e < 4; ++e) o[e] = (bf16)v[e];
    ((bf16x4*)out)[i] = o;
}

// ---------------------------------------------------------------------------
// W[K][N] f32  ->  Wt[N][K] bf16   (LDS-tiled transpose, 32x32 tiles)
__global__ __launch_bounds__(256)
void wconv(const float* __restrict__ W, bf16* __restrict__ Wt, int K, int N) {
    __shared__ float t[32][33];
    int n0 = blockIdx.x * 32, k0 = blockIdx.y * 32;
    int tx = threadIdx.x & 31, ty = threadIdx.x >> 5;  // 32 x 8
#pragma unroll
    for (int j = 0; j < 4; ++j)
        t[ty + j * 8][tx] = W[(size_t)(k0 + ty + j * 8) * N + n0 + tx];
    __syncthreads();
#pragma unroll
    for (int j = 0; j < 4; ++j)
        Wt[(size_t)(n0 + ty + j * 8) * K + k0 + tx] = (bf16)t[tx][ty + j * 8];
}

// ---------------------------------------------------------------------------
// C[M][N](bf16) = A[M][K](bf16) @ Bt[N][K]^T + bias, optional ReLU.
// 128x128 tile, BK=32, 4 waves (2x2). 2-phase double-buffered pipeline:
// issue next-tile global_load_lds BEFORE consuming current tile; the
// compiler's vmcnt(0)-drain at __syncthreads() overlaps loads with MFMA.
// XCD-aware flat-block swizzle (grids here are all %8==0 -> bijective).
template<bool RELU>
__global__ __launch_bounds__(256, 2)
void gemm_bf16(const bf16* __restrict__ A, const bf16* __restrict__ Bt,
               const float* __restrict__ bias, bf16* __restrict__ C,
               int M, int N, int K) {
    __shared__ alignas(16) bf16 Alds[2][128 * 32];
    __shared__ alignas(16) bf16 Blds[2][128 * 32];
    const int tid = threadIdx.x;
    const int wave = tid >> 6, lane = tid & 63;
    const int wr = wave >> 1, wc = wave & 1;

    // XCD swizzle: contiguous chunk of blocks per XCD
    const int nwg = gridDim.x * gridDim.y;
    const int flat = blockIdx.y * gridDim.x + blockIdx.x;
    const int swz = (flat & 7) * (nwg >> 3) + (flat >> 3);
    const int m0 = (swz / gridDim.x) * 128, n0 = (swz % gridDim.x) * 128;

    const int lr = lane & 15;          // A/B frag row (lane%16)
    const int lg = lane >> 4;          // k-group
    const int lk = lg * 8;             // k offset within 32

    const int srow = lane >> 2;        // staging row-in-16: 0..15
    const int scol = (lane & 3) * 8;   // staging col (elems)

    const bf16* Aw = A + (size_t)(m0 + wave * 32 + srow) * K + scol;
    const bf16* Bw = Bt + (size_t)(n0 + wave * 32 + srow) * K + scol;
    bf16* Adst0 = &Alds[0][(wave * 32) * 32];
    bf16* Bdst0 = &Blds[0][(wave * 32) * 32];

    f32x4 acc[4][4] = {};

    // prologue stage (buf 0, k=0)
    async_load16(Aw, Adst0);
    async_load16(Aw + (size_t)16 * K, Adst0 + 16 * 32);
    async_load16(Bw, Bdst0);
    async_load16(Bw + (size_t)16 * K, Bdst0 + 16 * 32);
    __syncthreads();

    const int nt = K >> 5;
    for (int t = 0; t < nt; ++t) {
        const int cur = t & 1;
        if (t + 1 < nt) {
            const size_t k0 = (size_t)(t + 1) << 5;
            bf16* Ad = &Alds[cur ^ 1][(wave * 32) * 32];
            bf16* Bd = &Blds[cur ^ 1][(wave * 32) * 32];
            async_load16(Aw + k0, Ad);
            async_load16(Aw + (size_t)16 * K + k0, Ad + 16 * 32);
            async_load16(Bw + k0, Bd);
            async_load16(Bw + (size_t)16 * K + k0, Bd + 16 * 32);
        }
        bf16x8 af[4], bfv[4];
#pragma unroll
        for (int i = 0; i < 4; ++i) {
            af[i]  = *(const bf16x8*)&Alds[cur][(wr * 64 + i * 16 + lr) * 32 + lk];
            bfv[i] = *(const bf16x8*)&Blds[cur][(wc * 64 + i * 16 + lr) * 32 + lk];
        }
#pragma unroll
        for (int mi = 0; mi < 4; ++mi)
#pragma unroll
            for (int ni = 0; ni < 4; ++ni)
                acc[mi][ni] = __builtin_amdgcn_mfma_f32_16x16x32_bf16(
                    af[mi], bfv[ni], acc[mi][ni], 0, 0, 0);
        __syncthreads();   // drains vmcnt(0): next buffer ready, cur reads done
    }

#pragma unroll
    for (int ni = 0; ni < 4; ++ni) {
        int n = n0 + wc * 64 + ni * 16 + lr;
        float bn = bias[n];
#pragma unroll
        for (int mi = 0; mi < 4; ++mi) {
#pragma unroll
            for (int r = 0; r < 4; ++r) {
                int m = m0 + wr * 64 + mi * 16 + lg * 4 + r;
                float v = acc[mi][ni][r] + bn;
                if (RELU) v = v > 0.f ? v : 0.f;
                C[(size_t)m * N + n] = (bf16)v;
            }
        }
    }
}

// ---------------------------------------------------------------------------
// Flash attention, KVBLK=64, XOR-swizzled LDS (conflict-free b128 reads).
// One block = (b, h, 64 q-rows); 4 waves x 16 q-rows.
// scores = (Q K^T) / 32 (reference scales by sqrt(D)=32, not sqrt(HD)).
// mask: kk < lk && q < lq && (!CAUSAL || kk <= q); fully-masked row -> 0.
template<bool CAUSAL>
__global__ __launch_bounds__(256, 4)
void attn_flash(const bf16* __restrict__ Qp, int qs,
                const bf16* __restrict__ Kp, int ks,
                const bf16* __restrict__ Vp, int vs,
                const int* __restrict__ Lq, const int* __restrict__ Lk,
                bf16* __restrict__ Op) {
    // K: [64 kk][64 d], row byte ^= ((kk&7)<<4); staged linear w/ pre-swizzled src
    // Vt: [64 d][64 k], row byte ^= ((d&7)<<4); reg-transposed
    // Plds: per-wave [16 q][64 kk], row byte ^= ((q&7)<<4)
    __shared__ alignas(16) bf16 Klds[64 * 64];
    __shared__ alignas(16) bf16 Vt[64 * 64];
    __shared__ alignas(16) bf16 Plds[4][16 * 64];

    const int tid = threadIdx.x;
    const int wave = tid >> 6, lane = tid & 63;
    const int qt = blockIdx.x, h = blockIdx.y, b = blockIdx.z;
    const int q0 = qt * 64;
    const int lq = Lq[b], lk = Lk[b];
    const int lr = lane & 15, lg = lane >> 4;

    char* KldsB = (char*)Klds;
    char* VtB = (char*)Vt;
    char* PldsB = (char*)&Plds[wave][0];

    // Q fragments (regs for whole KV loop): A-frag lane lr = q-row, lg*8+e = d
    bf16x8 aq[2];
    {
        const bf16* qrow = Qp + (size_t)(b * S_LEN + q0 + wave * 16 + lr) * qs + h * HDIM;
        aq[0] = *(const bf16x8*)(qrow + 0 + lg * 8);
        aq[1] = *(const bf16x8*)(qrow + 32 + lg * 8);
    }

    f32x4 o[4] = {};
    float m_run[4], l_run[4];
#pragma unroll
    for (int r = 0; r < 4; ++r) { m_run[r] = -INFINITY; l_run[r] = 0.f; }

    int kv_end = CAUSAL ? (q0 + 64) : S_LEN;
    int lk_cap = (lk + 63) & ~63;
    if (kv_end > lk_cap) kv_end = lk_cap;

    // V stage mapping: lane -> k, wave -> 16-d chunk
    const int vk = lane;
    const int vd0 = wave * 16;

    for (int kk0 = 0; kk0 < kv_end; kk0 += 64) {
        // --- stage K via global_load_lds: linear LDS dest, pre-swizzled source
#pragma unroll
        for (int c = 0; c < 2; ++c) {
            int rloc = c * 8 + (lane >> 3);               // row within wave's 16
            int row = wave * 16 + rloc;
            int chunk = (lane & 7) ^ (rloc & 7);          // row&7 == rloc&7
            async_load16(Kp + (size_t)(b * S_LEN + kk0 + row) * ks + h * HDIM + chunk * 8,
                         KldsB + (size_t)(wave * 16 + c * 8) * 128);
        }
        // --- stage V transposed (reg): thread (wave,lane) reads V[kk0+vk][vd0..+15]
        {
            const bf16* vsrc = Vp + (size_t)(b * S_LEN + kk0 + vk) * vs + h * HDIM + vd0;
            bf16x8 v0 = *(const bf16x8*)vsrc;
            bf16x8 v1 = *(const bf16x8*)(vsrc + 8);
#pragma unroll
            for (int e = 0; e < 8; ++e) {
                int d0 = vd0 + e, d1 = vd0 + 8 + e;
                *(bf16*)(VtB + (((size_t)d0 * 128 + vk * 2) ^ ((d0 & 7) << 4))) = v0[e];
                *(bf16*)(VtB + (((size_t)d1 * 128 + vk * 2) ^ ((d1 & 7) << 4))) = v1[e];
            }
        }
        __syncthreads();

        // --- S = Q K^T : 4 kt tiles of 16 kk, contraction d=64 via 2 mfma
        f32x4 sa[4];
#pragma unroll
        for (int kt = 0; kt < 4; ++kt) {
            int row = kt * 16 + lr;
            f32x4 z = {};
#pragma unroll
            for (int ds_ = 0; ds_ < 2; ++ds_) {
                bf16x8 bk = *(const bf16x8*)(KldsB +
                    (((size_t)row * 128 + ds_ * 64 + lg * 16) ^ ((row & 7) << 4)));
                z = __builtin_amdgcn_mfma_f32_16x16x32_bf16(aq[ds_], bk, z, 0, 0, 0);
            }
            sa[kt] = z;
        }

        // --- scale + mask + online softmax (q = q0 + wave*16 + lg*4 + r)
        float p[4][4];
#pragma unroll
        for (int r = 0; r < 4; ++r) {
            int q = q0 + wave * 16 + lg * 4 + r;
            float best = -INFINITY;
#pragma unroll
            for (int kt = 0; kt < 4; ++kt) {
                int kk = kk0 + kt * 16 + lr;
                float s = sa[kt][r] * 0.03125f;
                bool ok = (q < lq) && (kk < lk) && (!CAUSAL || kk <= q);
                s = ok ? s : -INFINITY;
                p[kt][r] = s;
                best = fmaxf(best, s);
            }
#pragma unroll
            for (int msk = 1; msk < 16; msk <<= 1)
                best = fmaxf(best, __shfl_xor(best, msk));
            float mn = fmaxf(m_run[r], best);
            float alpha = (m_run[r] == -INFINITY) ? 0.0f : __expf(m_run[r] - mn);
            float rs = 0.f;
#pragma unroll
            for (int kt = 0; kt < 4; ++kt) {
                float s = p[kt][r];
                float e = (s == -INFINITY) ? 0.f : __expf(s - mn);
                p[kt][r] = e;
                rs += e;
            }
#pragma unroll
            for (int msk = 1; msk < 16; msk <<= 1)
                rs += __shfl_xor(rs, msk);
            l_run[r] = l_run[r] * alpha + rs;
            m_run[r] = mn;
#pragma unroll
            for (int dt = 0; dt < 4; ++dt) o[dt][r] *= alpha;
        }

        // --- P (D-layout) -> per-wave swizzled LDS -> A-frag
#pragma unroll
        for (int kt = 0; kt < 4; ++kt)
#pragma unroll
            for (int r = 0; r < 4; ++r) {
                int ql = lg * 4 + r, kkl = kt * 16 + lr;
                *(bf16*)(PldsB + (((size_t)ql * 128 + kkl * 2) ^ ((ql & 7) << 4))) =
                    (bf16)p[kt][r];
            }
        bf16x8 pa[2];
#pragma unroll
        for (int ksl = 0; ksl < 2; ++ksl)
            pa[ksl] = *(const bf16x8*)(PldsB +
                (((size_t)lr * 128 + ksl * 64 + lg * 16) ^ ((lr & 7) << 4)));

        // --- O += P @ V  (B from Vt[d][k], contraction k=64 via 2 mfma)
#pragma unroll
        for (int dt = 0; dt < 4; ++dt) {
            int row = dt * 16 + lr;
#pragma unroll
            for (int ksl = 0; ksl < 2; ++ksl) {
                bf16x8 bv = *(const bf16x8*)(VtB +
                    (((size_t)row * 128 + ksl * 64 + lg * 16) ^ ((row & 7) << 4)));
                o[dt] = __builtin_amdgcn_mfma_f32_16x16x32_bf16(pa[ksl], bv, o[dt], 0, 0, 0);
            }
        }
        __syncthreads();
    }

    // epilogue: divide by row-sum (0 if fully masked), write [b,s, h*64+d]
#pragma unroll
    for (int dt = 0; dt < 4; ++dt) {
#pragma unroll
        for (int r = 0; r < 4; ++r) {
            int q = q0 + wave * 16 + lg * 4 + r;
            float denom = l_run[r];
            float val = denom > 0.f ? o[dt][r] / denom : 0.f;
            Op[(size_t)(b * S_LEN + q) * DMODEL + h * HDIM + dt * 16 + lr] = (bf16)val;
        }
    }
}

// ---------------------------------------------------------------------------
// y = LayerNorm(x_bf16 + rc_f32) * g + b ; writes f32 (optional) + bf16 (optional)
__global__ __launch_bounds__(256)
void ln_kernel(const bf16* __restrict__ x, const float* __restrict__ rc,
               const float* __restrict__ g, const float* __restrict__ beta,
               float* __restrict__ yf, bf16* __restrict__ yb) {
    const int row = blockIdx.x;
    const int tid = threadIdx.x;
    const int wave = tid >> 6, lane = tid & 63;
    const bf16* xr = x + (size_t)row * DMODEL;
    const float* rr = rc + (size_t)row * DMODEL;

    float v[4];
    {
        bf16x4 xv = *(const bf16x4*)(xr + tid * 4);
        f32x4 rv = *(const f32x4*)(rr + tid * 4);
#pragma unroll
        for (int i = 0; i < 4; ++i) v[i] = (float)xv[i] + rv[i];
    }
    float s = v[0] + v[1] + v[2] + v[3];
    float s2 = v[0] * v[0] + v[1] * v[1] + v[2] * v[2] + v[3] * v[3];
#pragma unroll
    for (int msk = 1; msk < 64; msk <<= 1) {
        s += __shfl_xor(s, msk);
        s2 += __shfl_xor(s2, msk);
    }
    __shared__ float red[8];
    if (lane == 0) { red[wave] = s; red[4 + wave] = s2; }
    __syncthreads();
    float ts = red[0] + red[1] + red[2] + red[3];
    float ts2 = red[4] + red[5] + red[6] + red[7];
    float mean = ts * (1.f / DMODEL);
    float var = ts2 * (1.f / DMODEL) - mean * mean;
    float inv = rsqrtf(var + 1e-5f);
#pragma unroll
    for (int i = 0; i < 4; ++i) {
        int c = tid * 4 + i;
        float yv = (v[i] - mean) * inv * g[c] + beta[c];
        if (yf) yf[(size_t)row * DMODEL + c] = yv;
        if (yb) yb[(size_t)row * DMODEL + c] = (bf16)yv;
    }
}

// ---------------------------------------------------------------------------
extern "C" void kernel_launch(void* const* d_in, const int* in_sizes, int n_in,
                              void* d_out, int out_size, void* d_ws, size_t ws_size,
                              hipStream_t stream) {
    const float* en     = (const float*)d_in[0];
    const float* fr     = (const float*)d_in[1];
    const float* W_attn = (const float*)d_in[2];
    const float* b_attn = (const float*)d_in[3];
    const float* W_Q    = (const float*)d_in[4];
    const float* b_Q    = (const float*)d_in[5];
    const float* W_KV   = (const float*)d_in[6];
    const float* b_KV   = (const float*)d_in[7];
    const float* ln_g   = (const float*)d_in[8];
    const float* ln_b   = (const float*)d_in[9];
    const float* W1     = (const float*)d_in[10];
    const float* b1     = (const float*)d_in[11];
    const float* W2     = (const float*)d_in[12];
    const float* b2     = (const float*)d_in[13];
    const int* l_en     = (const int*)d_in[14];
    const int* l_fr     = (const int*)d_in[15];
    float* out = (float*)d_out;

    char* ws = (char*)d_ws;
    const size_t MB = (size_t)1 << 20;
    bf16* Wt_attn = (bf16*)(ws + 0);        //  6 MB  [1024x3072]^T
    bf16* Wt_Q    = (bf16*)(ws + 6 * MB);   //  2 MB
    bf16* Wt_KV   = (bf16*)(ws + 8 * MB);   //  4 MB
    bf16* Wt_1    = (bf16*)(ws + 12 * MB);  //  8 MB
    bf16* Wt_2    = (bf16*)(ws + 20 * MB);  //  8 MB
    bf16* fr_bf   = (bf16*)(ws + 28 * MB);  //  8 MB
    bf16* en_bf   = (bf16*)(ws + 36 * MB);  //  8 MB
    bf16* bigA    = (bf16*)(ws + 44 * MB);  // 32 MB: qkv | (qc,kvc) | h
    bf16* xbuf    = (bf16*)(ws + 76 * MB);  //  8 MB: x1 | x2 | h2
    float* fr2    = (float*)(ws + 84 * MB); // 16 MB
    float* fr3    = (float*)(ws + 100 * MB);// 16 MB
    bf16* fbx     = (bf16*)(ws + 116 * MB); //  8 MB: fr2_bf then fr3_bf
    // total 124 MB

    dim3 blk(256);

    // converts + weight transposes
    cvt_f32_bf16<<<dim3(4096), blk, 0, stream>>>(fr, fr_bf, MROWS * DMODEL / 4);
    cvt_f32_bf16<<<dim3(4096), blk, 0, stream>>>(en, en_bf, MROWS * DMODEL / 4);
    wconv<<<dim3(96, 32), blk, 0, stream>>>(W_attn, Wt_attn, 1024, 3072);
    wconv<<<dim3(32, 32), blk, 0, stream>>>(W_Q, Wt_Q, 1024, 1024);
    wconv<<<dim3(64, 32), blk, 0, stream>>>(W_KV, Wt_KV, 1024, 2048);
    wconv<<<dim3(128, 32), blk, 0, stream>>>(W1, Wt_1, 1024, 4096);
    wconv<<<dim3(32, 128), blk, 0, stream>>>(W2, Wt_2, 4096, 1024);

    // --- self attention ---
    bf16* qkv = bigA;  // [4096][3072]
    gemm_bf16<false><<<dim3(24, 32), blk, 0, stream>>>(fr_bf, Wt_attn, b_attn, qkv, MROWS, 3072, 1024);
    attn_flash<true><<<dim3(16, NHEAD, BATCH), blk, 0, stream>>>(
        qkv, 3072, qkv + 1024, 3072, qkv + 2048, 3072, l_fr, l_fr, xbuf);
    ln_kernel<<<dim3(4096), blk, 0, stream>>>(xbuf, fr, ln_g, ln_b, fr2, fbx);

    // --- cross attention ---
    bf16* qc  = bigA;                                   // [4096][1024]
    bf16* kvc = (bf16*)((char*)bigA + 8 * MB);          // [4096][2048]
    gemm_bf16<false><<<dim3(8, 32), blk, 0, stream>>>(fbx, Wt_Q, b_Q, qc, MROWS, 1024, 1024);
    gemm_bf16<false><<<dim3(16, 32), blk, 0, stream>>>(en_bf, Wt_KV, b_KV, kvc, MROWS, 2048, 1024);
    attn_flash<false><<<dim3(16, NHEAD, BATCH), blk, 0, stream>>>(
        qc, 1024, kvc, 2048, kvc + 1024, 2048, l_fr, l_en, xbuf);
    ln_kernel<<<dim3(4096), blk, 0, stream>>>(xbuf, fr2, ln_g, ln_b, fr3, fbx);

    // --- FFN ---
    bf16* h = bigA;  // [4096][4096]
    gemm_bf16<true><<<dim3(32, 32), blk, 0, stream>>>(fbx, Wt_1, b1, h, MROWS, 4096, 1024);
    gemm_bf16<true><<<dim3(8, 32), blk, 0, stream>>>(h, Wt_2, b2, xbuf, MROWS, 1024, 4096);
    ln_kernel<<<dim3(4096), blk, 0, stream>>>(xbuf, fr3, ln_g, ln_b, out, nullptr);
}

// Round 4
// 344.055 us; speedup vs baseline: 1.2139x; 1.0253x over previous
//
#include <hip/hip_runtime.h>
#include <hip/hip_bf16.h>
#include <cstdint>
#include <cstddef>

#define S_LEN  1024
#define DMODEL 1024
#define NHEAD  16
#define HDIM   64
#define BATCH  4
#define MROWS  (BATCH * S_LEN)   // 4096

typedef __bf16 bf16;
typedef __attribute__((ext_vector_type(8))) __bf16 bf16x8;
typedef __attribute__((ext_vector_type(4))) __bf16 bf16x4;
typedef __attribute__((ext_vector_type(4))) float f32x4;
typedef __attribute__((ext_vector_type(4))) unsigned int u32x4;

// ---------------------------------------------------------------------------
// async global->LDS, 16B per lane. LDS dest must be wave-uniform base.
__device__ __forceinline__ void async_load16(const void* g, void* l) {
    __builtin_amdgcn_global_load_lds(
        (const __attribute__((address_space(1))) unsigned int*)g,
        (__attribute__((address_space(3))) unsigned int*)l,
        16, 0, 0);
}

// ---------------------------------------------------------------------------
// f32 -> bf16 elementwise convert (vectorized x4)
__global__ __launch_bounds__(256)
void cvt_f32_bf16(const float* __restrict__ in, bf16* __restrict__ out, int n4) {
    int i = blockIdx.x * 256 + threadIdx.x;
    if (i >= n4) return;
    f32x4 v = ((const f32x4*)in)[i];
    bf16x4 o;
#pragma unroll
    for (int e = 0; e < 4; ++e) o[e] = (bf16)v[e];
    ((bf16x4*)out)[i] = o;
}

// ---------------------------------------------------------------------------
// W[K][N] f32  ->  Wt[N][K] bf16   (LDS-tiled transpose, 32x32 tiles)
__global__ __launch_bounds__(256)
void wconv(const float* __restrict__ W, bf16* __restrict__ Wt, int K, int N) {
    __shared__ float t[32][33];
    int n0 = blockIdx.x * 32, k0 = blockIdx.y * 32;
    int tx = threadIdx.x & 31, ty = threadIdx.x >> 5;  // 32 x 8
#pragma unroll
    for (int j = 0; j < 4; ++j)
        t[ty + j * 8][tx] = W[(size_t)(k0 + ty + j * 8) * N + n0 + tx];
    __syncthreads();
#pragma unroll
    for (int j = 0; j < 4; ++j)
        Wt[(size_t)(n0 + ty + j * 8) * K + k0 + tx] = (bf16)t[tx][ty + j * 8];
}

// ---------------------------------------------------------------------------
// Shared GEMM core: 128x128 tile, BK=32, 4 waves (2x2), double-buffered
// 2-phase pipeline (issue next-tile global_load_lds before consuming current).
// A,Bt pre-offset to tile origin (and k-chunk start). lda/ldb = row strides.
__device__ __forceinline__ void gemm_acc(const bf16* __restrict__ A,
                                         const bf16* __restrict__ Bt,
                                         int Klen, int lda, int ldb,
                                         bf16* Alds, bf16* Blds,  // each [2][128*32]
                                         f32x4 acc[4][4]) {
    const int tid = threadIdx.x;
    const int wave = tid >> 6, lane = tid & 63;
    const int wr = wave >> 1, wc = wave & 1;
    const int lr = lane & 15, lg = lane >> 4, lk = lg * 8;
    const int srow = lane >> 2, scol = (lane & 3) * 8;

    const bf16* Aw = A + (size_t)(wave * 32 + srow) * lda + scol;
    const bf16* Bw = Bt + (size_t)(wave * 32 + srow) * ldb + scol;

    // prologue stage (buf 0)
    {
        bf16* Ad = Alds + (wave * 32) * 32;
        bf16* Bd = Blds + (wave * 32) * 32;
        async_load16(Aw, Ad);
        async_load16(Aw + (size_t)16 * lda, Ad + 16 * 32);
        async_load16(Bw, Bd);
        async_load16(Bw + (size_t)16 * ldb, Bd + 16 * 32);
    }
    __syncthreads();

    const int nt = Klen >> 5;
    for (int t = 0; t < nt; ++t) {
        const int cur = t & 1;
        if (t + 1 < nt) {
            const size_t k0 = (size_t)(t + 1) << 5;
            bf16* Ad = Alds + (cur ^ 1) * (128 * 32) + (wave * 32) * 32;
            bf16* Bd = Blds + (cur ^ 1) * (128 * 32) + (wave * 32) * 32;
            async_load16(Aw + k0, Ad);
            async_load16(Aw + (size_t)16 * lda + k0, Ad + 16 * 32);
            async_load16(Bw + k0, Bd);
            async_load16(Bw + (size_t)16 * ldb + k0, Bd + 16 * 32);
        }
        const bf16* Ab = Alds + cur * (128 * 32);
        const bf16* Bb = Blds + cur * (128 * 32);
        bf16x8 af[4], bfv[4];
#pragma unroll
        for (int i = 0; i < 4; ++i) {
            af[i]  = *(const bf16x8*)&Ab[(wr * 64 + i * 16 + lr) * 32 + lk];
            bfv[i] = *(const bf16x8*)&Bb[(wc * 64 + i * 16 + lr) * 32 + lk];
        }
#pragma unroll
        for (int mi = 0; mi < 4; ++mi)
#pragma unroll
            for (int ni = 0; ni < 4; ++ni)
                acc[mi][ni] = __builtin_amdgcn_mfma_f32_16x16x32_bf16(
                    af[mi], bfv[ni], acc[mi][ni], 0, 0, 0);
        __syncthreads();   // drains vmcnt(0): next buffer staged, cur reads done
    }
}

template<bool RELU>
__device__ __forceinline__ void epi_bf16(bf16* __restrict__ C, const float* __restrict__ bias,
                                         int N, int m0, int n0, f32x4 acc[4][4]) {
    const int tid = threadIdx.x;
    const int wave = tid >> 6, lane = tid & 63;
    const int wr = wave >> 1, wc = wave & 1;
    const int lr = lane & 15, lg = lane >> 4;
#pragma unroll
    for (int ni = 0; ni < 4; ++ni) {
        int n = n0 + wc * 64 + ni * 16 + lr;
        float bn = bias[n];
#pragma unroll
        for (int mi = 0; mi < 4; ++mi)
#pragma unroll
            for (int r = 0; r < 4; ++r) {
                int m = m0 + wr * 64 + mi * 16 + lg * 4 + r;
                float v = acc[mi][ni][r] + bn;
                if (RELU) v = v > 0.f ? v : 0.f;
                C[(size_t)m * N + n] = (bf16)v;
            }
    }
}

// ---------------------------------------------------------------------------
// Single GEMM, 1-D grid, XCD-swizzled (grid must be %8==0).
template<bool RELU>
__global__ __launch_bounds__(256, 2)
void gemm_one(const bf16* __restrict__ A, const bf16* __restrict__ Bt,
              const float* __restrict__ bias, bf16* __restrict__ C,
              int N, int K, int gx) {
    __shared__ alignas(16) bf16 Alds[2][128 * 32];
    __shared__ alignas(16) bf16 Blds[2][128 * 32];
    const int nwg = gridDim.x;
    const int flat = blockIdx.x;
    const int swz = (flat & 7) * (nwg >> 3) + (flat >> 3);
    const int m0 = (swz / gx) * 128, n0 = (swz % gx) * 128;
    f32x4 acc[4][4] = {};
    gemm_acc(A + (size_t)m0 * K, Bt + (size_t)n0 * K, K, K, K,
             &Alds[0][0], &Blds[0][0], acc);
    epi_bf16<RELU>(C, bias, N, m0, n0, acc);
}

// ---------------------------------------------------------------------------
// Two independent GEMMs in one launch (shared K): blocks [0,nwg0) -> g0.
struct GemmArgs {
    const bf16* A; const bf16* Bt; const float* bias; bf16* C; int N; int K; int gx;
};
__global__ __launch_bounds__(256, 2)
void gemm_dual(GemmArgs g0, int nwg0, GemmArgs g1) {
    __shared__ alignas(16) bf16 Alds[2][128 * 32];
    __shared__ alignas(16) bf16 Blds[2][128 * 32];
    const int nwg = gridDim.x;
    const int flat = blockIdx.x;
    const int swz = (flat & 7) * (nwg >> 3) + (flat >> 3);
    const bool first = swz < nwg0;
    const GemmArgs g = first ? g0 : g1;
    const int f = first ? swz : swz - nwg0;
    const int m0 = (f / g.gx) * 128, n0 = (f % g.gx) * 128;
    f32x4 acc[4][4] = {};
    gemm_acc(g.A + (size_t)m0 * g.K, g.Bt + (size_t)n0 * g.K, g.K, g.K, g.K,
             &Alds[0][0], &Blds[0][0], acc);
    epi_bf16<false>(g.C, g.bias, g.N, m0, n0, acc);
}

// ---------------------------------------------------------------------------
// Split-K GEMM (2 halves): blocks [0,256) -> k-half 0 -> P0; [256,512) -> P1.
// Writes f32 partials (no bias).
__global__ __launch_bounds__(256, 2)
void gemm_splitk2(const bf16* __restrict__ A, const bf16* __restrict__ Bt,
                  float* __restrict__ P0, float* __restrict__ P1,
                  int N, int K, int gx, int nwg_half) {
    __shared__ alignas(16) bf16 Alds[2][128 * 32];
    __shared__ alignas(16) bf16 Blds[2][128 * 32];
    const int nwg = gridDim.x;
    const int flat = blockIdx.x;
    const int swz = (flat & 7) * (nwg >> 3) + (flat >> 3);
    const int kz = swz >= nwg_half ? 1 : 0;
    const int f = swz - kz * nwg_half;
    const int m0 = (f / gx) * 128, n0 = (f % gx) * 128;
    const int Kh = K >> 1;
    const size_t koff = (size_t)kz * Kh;
    f32x4 acc[4][4] = {};
    gemm_acc(A + (size_t)m0 * K + koff, Bt + (size_t)n0 * K + koff, Kh, K, K,
             &Alds[0][0], &Blds[0][0], acc);
    float* P = kz ? P1 : P0;
    const int tid = threadIdx.x;
    const int wave = tid >> 6, lane = tid & 63;
    const int wr = wave >> 1, wc = wave & 1;
    const int lr = lane & 15, lg = lane >> 4;
#pragma unroll
    for (int ni = 0; ni < 4; ++ni) {
        int n = n0 + wc * 64 + ni * 16 + lr;
#pragma unroll
        for (int mi = 0; mi < 4; ++mi)
#pragma unroll
            for (int r = 0; r < 4; ++r) {
                int m = m0 + wr * 64 + mi * 16 + lg * 4 + r;
                P[(size_t)m * N + n] = acc[mi][ni][r];
            }
    }
}

// out = bf16( relu(P0 + P1 + bias) )   (FFN2 epilogue; N must divide by 4)
__global__ __launch_bounds__(256)
void splitk_reduce_relu(const float* __restrict__ P0, const float* __restrict__ P1,
                        const float* __restrict__ bias, bf16* __restrict__ C, int N) {
    int i = blockIdx.x * 256 + threadIdx.x;
    f32x4 a = ((const f32x4*)P0)[i];
    f32x4 b = ((const f32x4*)P1)[i];
    f32x4 bi = *(const f32x4*)(bias + ((i * 4) & (N - 1)));
    bf16x4 o;
#pragma unroll
    for (int e = 0; e < 4; ++e) {
        float v = a[e] + b[e] + bi[e];
        o[e] = (bf16)(v > 0.f ? v : 0.f);
    }
    ((bf16x4*)C)[i] = o;
}

// ---------------------------------------------------------------------------
// Flash attention, KVBLK=64, XOR-swizzled LDS (conflict-free b128 reads).
// One block = (b, h, 64 q-rows); 4 waves x 16 q-rows.
// scores = (Q K^T) / 32 (reference scales by sqrt(D)=32, not sqrt(HD)).
// mask: kk < lk && q < lq && (!CAUSAL || kk <= q); fully-masked row -> 0.
template<bool CAUSAL>
__global__ __launch_bounds__(256, 4)
void attn_flash(const bf16* __restrict__ Qp, int qs,
                const bf16* __restrict__ Kp, int ks,
                const bf16* __restrict__ Vp, int vs,
                const int* __restrict__ Lq, const int* __restrict__ Lk,
                bf16* __restrict__ Op) {
    __shared__ alignas(16) bf16 Klds[64 * 64];
    __shared__ alignas(16) bf16 Vt[64 * 64];
    __shared__ alignas(16) bf16 Plds[4][16 * 64];

    const int tid = threadIdx.x;
    const int wave = tid >> 6, lane = tid & 63;
    const int qt = blockIdx.x, h = blockIdx.y, b = blockIdx.z;
    const int q0 = qt * 64;
    const int lq = Lq[b], lk = Lk[b];
    const int lr = lane & 15, lg = lane >> 4;

    char* KldsB = (char*)Klds;
    char* VtB = (char*)Vt;
    char* PldsB = (char*)&Plds[wave][0];

    bf16x8 aq[2];
    {
        const bf16* qrow = Qp + (size_t)(b * S_LEN + q0 + wave * 16 + lr) * qs + h * HDIM;
        aq[0] = *(const bf16x8*)(qrow + 0 + lg * 8);
        aq[1] = *(const bf16x8*)(qrow + 32 + lg * 8);
    }

    f32x4 o[4] = {};
    float m_run[4], l_run[4];
#pragma unroll
    for (int r = 0; r < 4; ++r) { m_run[r] = -INFINITY; l_run[r] = 0.f; }

    int kv_end = CAUSAL ? (q0 + 64) : S_LEN;
    int lk_cap = (lk + 63) & ~63;
    if (kv_end > lk_cap) kv_end = lk_cap;

    const int vk = lane;
    const int vd0 = wave * 16;

    for (int kk0 = 0; kk0 < kv_end; kk0 += 64) {
#pragma unroll
        for (int c = 0; c < 2; ++c) {
            int rloc = c * 8 + (lane >> 3);
            int row = wave * 16 + rloc;
            int chunk = (lane & 7) ^ (rloc & 7);
            async_load16(Kp + (size_t)(b * S_LEN + kk0 + row) * ks + h * HDIM + chunk * 8,
                         KldsB + (size_t)(wave * 16 + c * 8) * 128);
        }
        {
            const bf16* vsrc = Vp + (size_t)(b * S_LEN + kk0 + vk) * vs + h * HDIM + vd0;
            bf16x8 v0 = *(const bf16x8*)vsrc;
            bf16x8 v1 = *(const bf16x8*)(vsrc + 8);
#pragma unroll
            for (int e = 0; e < 8; ++e) {
                int d0 = vd0 + e, d1 = vd0 + 8 + e;
                *(bf16*)(VtB + (((size_t)d0 * 128 + vk * 2) ^ ((d0 & 7) << 4))) = v0[e];
                *(bf16*)(VtB + (((size_t)d1 * 128 + vk * 2) ^ ((d1 & 7) << 4))) = v1[e];
            }
        }
        __syncthreads();

        f32x4 sa[4];
#pragma unroll
        for (int kt = 0; kt < 4; ++kt) {
            int row = kt * 16 + lr;
            f32x4 z = {};
#pragma unroll
            for (int ds_ = 0; ds_ < 2; ++ds_) {
                bf16x8 bk = *(const bf16x8*)(KldsB +
                    (((size_t)row * 128 + ds_ * 64 + lg * 16) ^ ((row & 7) << 4)));
                z = __builtin_amdgcn_mfma_f32_16x16x32_bf16(aq[ds_], bk, z, 0, 0, 0);
            }
            sa[kt] = z;
        }

        float p[4][4];
#pragma unroll
        for (int r = 0; r < 4; ++r) {
            int q = q0 + wave * 16 + lg * 4 + r;
            float best = -INFINITY;
#pragma unroll
            for (int kt = 0; kt < 4; ++kt) {
                int kk = kk0 + kt * 16 + lr;
                float s = sa[kt][r] * 0.03125f;
                bool ok = (q < lq) && (kk < lk) && (!CAUSAL || kk <= q);
                s = ok ? s : -INFINITY;
                p[kt][r] = s;
                best = fmaxf(best, s);
            }
#pragma unroll
            for (int msk = 1; msk < 16; msk <<= 1)
                best = fmaxf(best, __shfl_xor(best, msk));
            float mn = fmaxf(m_run[r], best);
            float alpha = (m_run[r] == -INFINITY) ? 0.0f : __expf(m_run[r] - mn);
            float rs = 0.f;
#pragma unroll
            for (int kt = 0; kt < 4; ++kt) {
                float s = p[kt][r];
                float e = (s == -INFINITY) ? 0.f : __expf(s - mn);
                p[kt][r] = e;
                rs += e;
            }
#pragma unroll
            for (int msk = 1; msk < 16; msk <<= 1)
                rs += __shfl_xor(rs, msk);
            l_run[r] = l_run[r] * alpha + rs;
            m_run[r] = mn;
#pragma unroll
            for (int dt = 0; dt < 4; ++dt) o[dt][r] *= alpha;
        }

#pragma unroll
        for (int kt = 0; kt < 4; ++kt)
#pragma unroll
            for (int r = 0; r < 4; ++r) {
                int ql = lg * 4 + r, kkl = kt * 16 + lr;
                *(bf16*)(PldsB + (((size_t)ql * 128 + kkl * 2) ^ ((ql & 7) << 4))) =
                    (bf16)p[kt][r];
            }
        bf16x8 pa[2];
#pragma unroll
        for (int ksl = 0; ksl < 2; ++ksl)
            pa[ksl] = *(const bf16x8*)(PldsB +
                (((size_t)lr * 128 + ksl * 64 + lg * 16) ^ ((lr & 7) << 4)));

#pragma unroll
        for (int dt = 0; dt < 4; ++dt) {
            int row = dt * 16 + lr;
#pragma unroll
            for (int ksl = 0; ksl < 2; ++ksl) {
                bf16x8 bv = *(const bf16x8*)(VtB +
                    (((size_t)row * 128 + ksl * 64 + lg * 16) ^ ((row & 7) << 4)));
                o[dt] = __builtin_amdgcn_mfma_f32_16x16x32_bf16(pa[ksl], bv, o[dt], 0, 0, 0);
            }
        }
        __syncthreads();
    }

#pragma unroll
    for (int dt = 0; dt < 4; ++dt) {
#pragma unroll
        for (int r = 0; r < 4; ++r) {
            int q = q0 + wave * 16 + lg * 4 + r;
            float denom = l_run[r];
            float val = denom > 0.f ? o[dt][r] / denom : 0.f;
            Op[(size_t)(b * S_LEN + q) * DMODEL + h * HDIM + dt * 16 + lr] = (bf16)val;
        }
    }
}

// ---------------------------------------------------------------------------
// y = LayerNorm(x_bf16 + rc_f32) * g + b ; writes f32 (optional) + bf16 (optional)
__global__ __launch_bounds__(256)
void ln_kernel(const bf16* __restrict__ x, const float* __restrict__ rc,
               const float* __restrict__ g, const float* __restrict__ beta,
               float* __restrict__ yf, bf16* __restrict__ yb) {
    const int row = blockIdx.x;
    const int tid = threadIdx.x;
    const int wave = tid >> 6, lane = tid & 63;
    const bf16* xr = x + (size_t)row * DMODEL;
    const float* rr = rc + (size_t)row * DMODEL;

    float v[4];
    {
        bf16x4 xv = *(const bf16x4*)(xr + tid * 4);
        f32x4 rv = *(const f32x4*)(rr + tid * 4);
#pragma unroll
        for (int i = 0; i < 4; ++i) v[i] = (float)xv[i] + rv[i];
    }
    float s = v[0] + v[1] + v[2] + v[3];
    float s2 = v[0] * v[0] + v[1] * v[1] + v[2] * v[2] + v[3] * v[3];
#pragma unroll
    for (int msk = 1; msk < 64; msk <<= 1) {
        s += __shfl_xor(s, msk);
        s2 += __shfl_xor(s2, msk);
    }
    __shared__ float red[8];
    if (lane == 0) { red[wave] = s; red[4 + wave] = s2; }
    __syncthreads();
    float ts = red[0] + red[1] + red[2] + red[3];
    float ts2 = red[4] + red[5] + red[6] + red[7];
    float mean = ts * (1.f / DMODEL);
    float var = ts2 * (1.f / DMODEL) - mean * mean;
    float inv = rsqrtf(var + 1e-5f);
#pragma unroll
    for (int i = 0; i < 4; ++i) {
        int c = tid * 4 + i;
        float yv = (v[i] - mean) * inv * g[c] + beta[c];
        if (yf) yf[(size_t)row * DMODEL + c] = yv;
        if (yb) yb[(size_t)row * DMODEL + c] = (bf16)yv;
    }
}

// ---------------------------------------------------------------------------
extern "C" void kernel_launch(void* const* d_in, const int* in_sizes, int n_in,
                              void* d_out, int out_size, void* d_ws, size_t ws_size,
                              hipStream_t stream) {
    const float* en     = (const float*)d_in[0];
    const float* fr     = (const float*)d_in[1];
    const float* W_attn = (const float*)d_in[2];
    const float* b_attn = (const float*)d_in[3];
    const float* W_Q    = (const float*)d_in[4];
    const float* b_Q    = (const float*)d_in[5];
    const float* W_KV   = (const float*)d_in[6];
    const float* b_KV   = (const float*)d_in[7];
    const float* ln_g   = (const float*)d_in[8];
    const float* ln_b   = (const float*)d_in[9];
    const float* W1     = (const float*)d_in[10];
    const float* b1     = (const float*)d_in[11];
    const float* W2     = (const float*)d_in[12];
    const float* b2     = (const float*)d_in[13];
    const int* l_en     = (const int*)d_in[14];
    const int* l_fr     = (const int*)d_in[15];
    float* out = (float*)d_out;

    char* ws = (char*)d_ws;
    const size_t MB = (size_t)1 << 20;
    bf16* Wt_attn = (bf16*)(ws + 0);        //  6 MB (dead after dual-gemm; P0 reuse)
    bf16* Wt_Q    = (bf16*)(ws + 6 * MB);   //  2 MB
    bf16* Wt_KV   = (bf16*)(ws + 8 * MB);   //  4 MB
    bf16* Wt_1    = (bf16*)(ws + 12 * MB);  //  8 MB (dead after FFN1)
    bf16* Wt_2    = (bf16*)(ws + 20 * MB);  //  8 MB (live through FFN2)
    bf16* fr_bf   = (bf16*)(ws + 28 * MB);  //  8 MB (dead after dual-gemm; P1 reuse)
    bf16* en_bf   = (bf16*)(ws + 36 * MB);  //  8 MB (dead after dual-gemm; P1 reuse)
    bf16* bigA    = (bf16*)(ws + 44 * MB);  // 32 MB: qkv | qc | h
    bf16* xbuf    = (bf16*)(ws + 76 * MB);  //  8 MB: x1 | x2 | h2
    float* fr2    = (float*)(ws + 84 * MB); // 16 MB
    float* fr3    = (float*)(ws + 100 * MB);// 16 MB (kvc lives here until LN2)
    bf16* fbx     = (bf16*)(ws + 116 * MB); //  8 MB: fr2_bf then fr3_bf
    // split-K partials (stream-order-safe reuse):
    float* P0 = (float*)(ws + 0);           // 16 MB over Wt_attn/Q/KV/Wt_1[0:4MB]
    float* P1 = (float*)(ws + 28 * MB);     // 16 MB over fr_bf/en_bf
    bf16* kvc = (bf16*)(ws + 100 * MB);     // 16 MB, overwritten by fr3 at LN2
    // total 124 MB

    dim3 blk(256);

    cvt_f32_bf16<<<dim3(4096), blk, 0, stream>>>(fr, fr_bf, MROWS * DMODEL / 4);
    cvt_f32_bf16<<<dim3(4096), blk, 0, stream>>>(en, en_bf, MROWS * DMODEL / 4);
    wconv<<<dim3(96, 32), blk, 0, stream>>>(W_attn, Wt_attn, 1024, 3072);
    wconv<<<dim3(32, 32), blk, 0, stream>>>(W_Q, Wt_Q, 1024, 1024);
    wconv<<<dim3(64, 32), blk, 0, stream>>>(W_KV, Wt_KV, 1024, 2048);
    wconv<<<dim3(128, 32), blk, 0, stream>>>(W1, Wt_1, 1024, 4096);
    wconv<<<dim3(32, 128), blk, 0, stream>>>(W2, Wt_2, 4096, 1024);

    // --- fused: self-attn QKV proj (768 wg) + cross KV proj (512 wg) ---
    bf16* qkv = bigA;  // [4096][3072]
    GemmArgs gq{fr_bf, Wt_attn, b_attn, qkv, 3072, 1024, 24};
    GemmArgs gk{en_bf, Wt_KV, b_KV, kvc, 2048, 1024, 16};
    gemm_dual<<<dim3(1280), blk, 0, stream>>>(gq, 768, gk);

    // --- self attention ---
    attn_flash<true><<<dim3(16, NHEAD, BATCH), blk, 0, stream>>>(
        qkv, 3072, qkv + 1024, 3072, qkv + 2048, 3072, l_fr, l_fr, xbuf);
    ln_kernel<<<dim3(4096), blk, 0, stream>>>(xbuf, fr, ln_g, ln_b, fr2, fbx);

    // --- cross attention ---
    bf16* qc = bigA;  // [4096][1024] (qkv dead after attn1)
    gemm_one<false><<<dim3(256), blk, 0, stream>>>(fbx, Wt_Q, b_Q, qc, 1024, 1024, 8);
    attn_flash<false><<<dim3(16, NHEAD, BATCH), blk, 0, stream>>>(
        qc, 1024, kvc, 2048, kvc + 1024, 2048, l_fr, l_en, xbuf);
    ln_kernel<<<dim3(4096), blk, 0, stream>>>(xbuf, fr2, ln_g, ln_b, fr3, fbx);

    // --- FFN ---
    bf16* h = bigA;  // [4096][4096]
    gemm_one<true><<<dim3(1024), blk, 0, stream>>>(fbx, Wt_1, b1, h, 4096, 1024, 32);
    gemm_splitk2<<<dim3(512), blk, 0, stream>>>(h, Wt_2, P0, P1, 1024, 4096, 8, 256);
    splitk_reduce_relu<<<dim3(4096), blk, 0, stream>>>(P0, P1, b2, xbuf, 1024);
    ln_kernel<<<dim3(4096), blk, 0, stream>>>(xbuf, fr3, ln_g, ln_b, out, nullptr);
}

// Round 5
// 341.835 us; speedup vs baseline: 1.2218x; 1.0065x over previous
//
#include <hip/hip_runtime.h>
#include <hip/hip_bf16.h>
#include <cstdint>
#include <cstddef>

#define S_LEN  1024
#define DMODEL 1024
#define NHEAD  16
#define HDIM   64
#define BATCH  4
#define MROWS  (BATCH * S_LEN)   // 4096

typedef __bf16 bf16;
typedef __attribute__((ext_vector_type(8))) __bf16 bf16x8;
typedef __attribute__((ext_vector_type(4))) __bf16 bf16x4;
typedef __attribute__((ext_vector_type(4))) float f32x4;
typedef __attribute__((ext_vector_type(4))) unsigned int u32x4;

// ---------------------------------------------------------------------------
// async global->LDS, 16B per lane. LDS dest must be wave-uniform base.
__device__ __forceinline__ void async_load16(const void* g, void* l) {
    __builtin_amdgcn_global_load_lds(
        (const __attribute__((address_space(1))) unsigned int*)g,
        (__attribute__((address_space(3))) unsigned int*)l,
        16, 0, 0);
}

// ---------------------------------------------------------------------------
// f32 -> bf16 convert for fr and en in one launch (each n4 = MROWS*DMODEL/4)
__global__ __launch_bounds__(256)
void cvt_two(const float* __restrict__ in0, bf16* __restrict__ out0,
             const float* __restrict__ in1, bf16* __restrict__ out1, int n4) {
    int i = blockIdx.x * 256 + threadIdx.x;
    const float* in = in0; bf16* out = out0;
    if (i >= n4) { i -= n4; in = in1; out = out1; }
    f32x4 v = ((const f32x4*)in)[i];
    bf16x4 o;
#pragma unroll
    for (int e = 0; e < 4; ++e) o[e] = (bf16)v[e];
    ((bf16x4*)out)[i] = o;
}

// ---------------------------------------------------------------------------
// All 5 weight transposes (W[K][N] f32 -> Wt[N][K] bf16) in one launch.
// Tile counts: attn 96x32=3072 | Q 32x32=1024 | KV 64x32=2048 | W1 128x32=4096
// | W2 32x128=4096  => 14336 blocks total.
__global__ __launch_bounds__(256)
void wconv_all(const float* __restrict__ Wa, bf16* __restrict__ Ta,
               const float* __restrict__ Wq, bf16* __restrict__ Tq,
               const float* __restrict__ Wkv, bf16* __restrict__ Tkv,
               const float* __restrict__ W1, bf16* __restrict__ T1,
               const float* __restrict__ W2, bf16* __restrict__ T2) {
    __shared__ float t[32][33];
    int id = blockIdx.x;
    const float* W; bf16* Wt; int K, N, nx, base;
    if (id < 3072)       { W = Wa;  Wt = Ta;  K = 1024; N = 3072; nx = 96;  base = 0; }
    else if (id < 4096)  { W = Wq;  Wt = Tq;  K = 1024; N = 1024; nx = 32;  base = 3072; }
    else if (id < 6144)  { W = Wkv; Wt = Tkv; K = 1024; N = 2048; nx = 64;  base = 4096; }
    else if (id < 10240) { W = W1;  Wt = T1;  K = 1024; N = 4096; nx = 128; base = 6144; }
    else                 { W = W2;  Wt = T2;  K = 4096; N = 1024; nx = 32;  base = 10240; }
    int loc = id - base;
    int n0 = (loc % nx) * 32, k0 = (loc / nx) * 32;
    int tx = threadIdx.x & 31, ty = threadIdx.x >> 5;  // 32 x 8
#pragma unroll
    for (int j = 0; j < 4; ++j)
        t[ty + j * 8][tx] = W[(size_t)(k0 + ty + j * 8) * N + n0 + tx];
    __syncthreads();
#pragma unroll
    for (int j = 0; j < 4; ++j)
        Wt[(size_t)(n0 + ty + j * 8) * K + k0 + tx] = (bf16)t[tx][ty + j * 8];
}

// ---------------------------------------------------------------------------
// GEMM core: 128x128 tile, BK=32, 4 waves (2x2). 3-deep LDS pipeline with
// COUNTED vmcnt (T4): at iter t issue loads for tile t+2, then wait vmcnt(4)
// (t+1's 4 loads retired, t+2's still in flight) + lgkmcnt(0) + raw barrier.
// sched_barrier(0) fences prevent hipcc hoisting ds_reads across (rule #18).
// Requires Klen >= 64 (nt >= 2). LDS: 3 bufs x 8KB x {A,B} = 48 KB.
__device__ __forceinline__ void gemm_acc(const bf16* __restrict__ A,
                                         const bf16* __restrict__ Bt,
                                         int Klen, int lda, int ldb,
                                         bf16* Alds, bf16* Blds,  // each [3][128*32]
                                         f32x4 acc[4][4]) {
    const int tid = threadIdx.x;
    const int wave = tid >> 6, lane = tid & 63;
    const int wr = wave >> 1, wc = wave & 1;
    const int lr = lane & 15, lg = lane >> 4, lk = lg * 8;
    const int srow = lane >> 2, scol = (lane & 3) * 8;

    const bf16* Aw = A + (size_t)(wave * 32 + srow) * lda + scol;
    const bf16* Bw = Bt + (size_t)(wave * 32 + srow) * ldb + scol;
    const int ldsw = (wave * 32) * 32;

    const int nt = Klen >> 5;   // >= 2 at every call site

    // prologue: tiles 0,1 into bufs 0,1
    async_load16(Aw, Alds + ldsw);
    async_load16(Aw + (size_t)16 * lda, Alds + ldsw + 16 * 32);
    async_load16(Bw, Blds + ldsw);
    async_load16(Bw + (size_t)16 * ldb, Blds + ldsw + 16 * 32);
    async_load16(Aw + 32, Alds + 128 * 32 + ldsw);
    async_load16(Aw + (size_t)16 * lda + 32, Alds + 128 * 32 + ldsw + 16 * 32);
    async_load16(Bw + 32, Blds + 128 * 32 + ldsw);
    async_load16(Bw + (size_t)16 * ldb + 32, Blds + 128 * 32 + ldsw + 16 * 32);
    asm volatile("s_waitcnt vmcnt(4)" ::: "memory");   // tile 0 landed
    __builtin_amdgcn_sched_barrier(0);
    __builtin_amdgcn_s_barrier();
    __builtin_amdgcn_sched_barrier(0);

    int cur = 0;
    for (int t = 0; t < nt; ++t) {
        if (t + 2 < nt) {
            int nb = cur + 2; if (nb >= 3) nb -= 3;
            const size_t k0 = (size_t)(t + 2) << 5;
            bf16* Ad = Alds + nb * (128 * 32) + ldsw;
            bf16* Bd = Blds + nb * (128 * 32) + ldsw;
            async_load16(Aw + k0, Ad);
            async_load16(Aw + (size_t)16 * lda + k0, Ad + 16 * 32);
            async_load16(Bw + k0, Bd);
            async_load16(Bw + (size_t)16 * ldb + k0, Bd + 16 * 32);
        }
        const bf16* Ab = Alds + cur * (128 * 32);
        const bf16* Bb = Blds + cur * (128 * 32);
        bf16x8 af[4], bfv[4];
#pragma unroll
        for (int i = 0; i < 4; ++i) {
            af[i]  = *(const bf16x8*)&Ab[(wr * 64 + i * 16 + lr) * 32 + lk];
            bfv[i] = *(const bf16x8*)&Bb[(wc * 64 + i * 16 + lr) * 32 + lk];
        }
#pragma unroll
        for (int mi = 0; mi < 4; ++mi)
#pragma unroll
            for (int ni = 0; ni < 4; ++ni)
                acc[mi][ni] = __builtin_amdgcn_mfma_f32_16x16x32_bf16(
                    af[mi], bfv[ni], acc[mi][ni], 0, 0, 0);
        if (t + 1 < nt) {
            if (t + 2 < nt) asm volatile("s_waitcnt vmcnt(4)" ::: "memory");
            else            asm volatile("s_waitcnt vmcnt(0)" ::: "memory");
            asm volatile("s_waitcnt lgkmcnt(0)" ::: "memory");
            __builtin_amdgcn_sched_barrier(0);
            __builtin_amdgcn_s_barrier();
            __builtin_amdgcn_sched_barrier(0);
        }
        cur = cur + 1 == 3 ? 0 : cur + 1;
    }
}

template<bool RELU>
__device__ __forceinline__ void epi_bf16(bf16* __restrict__ C, const float* __restrict__ bias,
                                         int N, int m0, int n0, f32x4 acc[4][4]) {
    const int tid = threadIdx.x;
    const int wave = tid >> 6, lane = tid & 63;
    const int wr = wave >> 1, wc = wave & 1;
    const int lr = lane & 15, lg = lane >> 4;
#pragma unroll
    for (int ni = 0; ni < 4; ++ni) {
        int n = n0 + wc * 64 + ni * 16 + lr;
        float bn = bias[n];
#pragma unroll
        for (int mi = 0; mi < 4; ++mi)
#pragma unroll
            for (int r = 0; r < 4; ++r) {
                int m = m0 + wr * 64 + mi * 16 + lg * 4 + r;
                float v = acc[mi][ni][r] + bn;
                if (RELU) v = v > 0.f ? v : 0.f;
                C[(size_t)m * N + n] = (bf16)v;
            }
    }
}

// ---------------------------------------------------------------------------
// Single GEMM, 1-D grid, XCD-swizzled (grid must be %8==0).
template<bool RELU>
__global__ __launch_bounds__(256, 2)
void gemm_one(const bf16* __restrict__ A, const bf16* __restrict__ Bt,
              const float* __restrict__ bias, bf16* __restrict__ C,
              int N, int K, int gx) {
    __shared__ alignas(16) bf16 Alds[3][128 * 32];
    __shared__ alignas(16) bf16 Blds[3][128 * 32];
    const int nwg = gridDim.x;
    const int flat = blockIdx.x;
    const int swz = (flat & 7) * (nwg >> 3) + (flat >> 3);
    const int m0 = (swz / gx) * 128, n0 = (swz % gx) * 128;
    f32x4 acc[4][4] = {};
    gemm_acc(A + (size_t)m0 * K, Bt + (size_t)n0 * K, K, K, K,
             &Alds[0][0], &Blds[0][0], acc);
    epi_bf16<RELU>(C, bias, N, m0, n0, acc);
}

// ---------------------------------------------------------------------------
// Two independent GEMMs in one launch (shared K): blocks [0,nwg0) -> g0.
struct GemmArgs {
    const bf16* A; const bf16* Bt; const float* bias; bf16* C; int N; int K; int gx;
};
__global__ __launch_bounds__(256, 2)
void gemm_dual(GemmArgs g0, int nwg0, GemmArgs g1) {
    __shared__ alignas(16) bf16 Alds[3][128 * 32];
    __shared__ alignas(16) bf16 Blds[3][128 * 32];
    const int nwg = gridDim.x;
    const int flat = blockIdx.x;
    const int swz = (flat & 7) * (nwg >> 3) + (flat >> 3);
    const bool first = swz < nwg0;
    const GemmArgs g = first ? g0 : g1;
    const int f = first ? swz : swz - nwg0;
    const int m0 = (f / g.gx) * 128, n0 = (f % g.gx) * 128;
    f32x4 acc[4][4] = {};
    gemm_acc(g.A + (size_t)m0 * g.K, g.Bt + (size_t)n0 * g.K, g.K, g.K, g.K,
             &Alds[0][0], &Blds[0][0], acc);
    epi_bf16<false>(g.C, g.bias, g.N, m0, n0, acc);
}

// ---------------------------------------------------------------------------
// Split-K GEMM (2 halves): writes f32 partials (no bias).
__global__ __launch_bounds__(256, 2)
void gemm_splitk2(const bf16* __restrict__ A, const bf16* __restrict__ Bt,
                  float* __restrict__ P0, float* __restrict__ P1,
                  int N, int K, int gx, int nwg_half) {
    __shared__ alignas(16) bf16 Alds[3][128 * 32];
    __shared__ alignas(16) bf16 Blds[3][128 * 32];
    const int nwg = gridDim.x;
    const int flat = blockIdx.x;
    const int swz = (flat & 7) * (nwg >> 3) + (flat >> 3);
    const int kz = swz >= nwg_half ? 1 : 0;
    const int f = swz - kz * nwg_half;
    const int m0 = (f / gx) * 128, n0 = (f % gx) * 128;
    const int Kh = K >> 1;
    const size_t koff = (size_t)kz * Kh;
    f32x4 acc[4][4] = {};
    gemm_acc(A + (size_t)m0 * K + koff, Bt + (size_t)n0 * K + koff, Kh, K, K,
             &Alds[0][0], &Blds[0][0], acc);
    float* P = kz ? P1 : P0;
    const int tid = threadIdx.x;
    const int wave = tid >> 6, lane = tid & 63;
    const int wr = wave >> 1, wc = wave & 1;
    const int lr = lane & 15, lg = lane >> 4;
#pragma unroll
    for (int ni = 0; ni < 4; ++ni) {
        int n = n0 + wc * 64 + ni * 16 + lr;
#pragma unroll
        for (int mi = 0; mi < 4; ++mi)
#pragma unroll
            for (int r = 0; r < 4; ++r) {
                int m = m0 + wr * 64 + mi * 16 + lg * 4 + r;
                P[(size_t)m * N + n] = acc[mi][ni][r];
            }
    }
}

// ---------------------------------------------------------------------------
// Flash attention, KVBLK=64, XOR-swizzled LDS (conflict-free b128 reads).
// One block = (b, h, 64 q-rows); 4 waves x 16 q-rows.
// scores = (Q K^T) / 32 (reference scales by sqrt(D)=32, not sqrt(HD)).
// mask: kk < lk && q < lq && (!CAUSAL || kk <= q); fully-masked row -> 0.
template<bool CAUSAL>
__global__ __launch_bounds__(256, 4)
void attn_flash(const bf16* __restrict__ Qp, int qs,
                const bf16* __restrict__ Kp, int ks,
                const bf16* __restrict__ Vp, int vs,
                const int* __restrict__ Lq, const int* __restrict__ Lk,
                bf16* __restrict__ Op) {
    __shared__ alignas(16) bf16 Klds[64 * 64];
    __shared__ alignas(16) bf16 Vt[64 * 64];
    __shared__ alignas(16) bf16 Plds[4][16 * 64];

    const int tid = threadIdx.x;
    const int wave = tid >> 6, lane = tid & 63;
    const int qt = blockIdx.x, h = blockIdx.y, b = blockIdx.z;
    const int q0 = qt * 64;
    const int lq = Lq[b], lk = Lk[b];
    const int lr = lane & 15, lg = lane >> 4;

    char* KldsB = (char*)Klds;
    char* VtB = (char*)Vt;
    char* PldsB = (char*)&Plds[wave][0];

    bf16x8 aq[2];
    {
        const bf16* qrow = Qp + (size_t)(b * S_LEN + q0 + wave * 16 + lr) * qs + h * HDIM;
        aq[0] = *(const bf16x8*)(qrow + 0 + lg * 8);
        aq[1] = *(const bf16x8*)(qrow + 32 + lg * 8);
    }

    f32x4 o[4] = {};
    float m_run[4], l_run[4];
#pragma unroll
    for (int r = 0; r < 4; ++r) { m_run[r] = -INFINITY; l_run[r] = 0.f; }

    int kv_end = CAUSAL ? (q0 + 64) : S_LEN;
    int lk_cap = (lk + 63) & ~63;
    if (kv_end > lk_cap) kv_end = lk_cap;

    const int vk = lane;
    const int vd0 = wave * 16;

    for (int kk0 = 0; kk0 < kv_end; kk0 += 64) {
#pragma unroll
        for (int c = 0; c < 2; ++c) {
            int rloc = c * 8 + (lane >> 3);
            int row = wave * 16 + rloc;
            int chunk = (lane & 7) ^ (rloc & 7);
            async_load16(Kp + (size_t)(b * S_LEN + kk0 + row) * ks + h * HDIM + chunk * 8,
                         KldsB + (size_t)(wave * 16 + c * 8) * 128);
        }
        {
            const bf16* vsrc = Vp + (size_t)(b * S_LEN + kk0 + vk) * vs + h * HDIM + vd0;
            bf16x8 v0 = *(const bf16x8*)vsrc;
            bf16x8 v1 = *(const bf16x8*)(vsrc + 8);
#pragma unroll
            for (int e = 0; e < 8; ++e) {
                int d0 = vd0 + e, d1 = vd0 + 8 + e;
                *(bf16*)(VtB + (((size_t)d0 * 128 + vk * 2) ^ ((d0 & 7) << 4))) = v0[e];
                *(bf16*)(VtB + (((size_t)d1 * 128 + vk * 2) ^ ((d1 & 7) << 4))) = v1[e];
            }
        }
        __syncthreads();

        f32x4 sa[4];
#pragma unroll
        for (int kt = 0; kt < 4; ++kt) {
            int row = kt * 16 + lr;
            f32x4 z = {};
#pragma unroll
            for (int ds_ = 0; ds_ < 2; ++ds_) {
                bf16x8 bk = *(const bf16x8*)(KldsB +
                    (((size_t)row * 128 + ds_ * 64 + lg * 16) ^ ((row & 7) << 4)));
                z = __builtin_amdgcn_mfma_f32_16x16x32_bf16(aq[ds_], bk, z, 0, 0, 0);
            }
            sa[kt] = z;
        }

        float p[4][4];
#pragma unroll
        for (int r = 0; r < 4; ++r) {
            int q = q0 + wave * 16 + lg * 4 + r;
            float best = -INFINITY;
#pragma unroll
            for (int kt = 0; kt < 4; ++kt) {
                int kk = kk0 + kt * 16 + lr;
                float s = sa[kt][r] * 0.03125f;
                bool ok = (q < lq) && (kk < lk) && (!CAUSAL || kk <= q);
                s = ok ? s : -INFINITY;
                p[kt][r] = s;
                best = fmaxf(best, s);
            }
#pragma unroll
            for (int msk = 1; msk < 16; msk <<= 1)
                best = fmaxf(best, __shfl_xor(best, msk));
            float mn = fmaxf(m_run[r], best);
            float alpha = (m_run[r] == -INFINITY) ? 0.0f : __expf(m_run[r] - mn);
            float rs = 0.f;
#pragma unroll
            for (int kt = 0; kt < 4; ++kt) {
                float s = p[kt][r];
                float e = (s == -INFINITY) ? 0.f : __expf(s - mn);
                p[kt][r] = e;
                rs += e;
            }
#pragma unroll
            for (int msk = 1; msk < 16; msk <<= 1)
                rs += __shfl_xor(rs, msk);
            l_run[r] = l_run[r] * alpha + rs;
            m_run[r] = mn;
#pragma unroll
            for (int dt = 0; dt < 4; ++dt) o[dt][r] *= alpha;
        }

#pragma unroll
        for (int kt = 0; kt < 4; ++kt)
#pragma unroll
            for (int r = 0; r < 4; ++r) {
                int ql = lg * 4 + r, kkl = kt * 16 + lr;
                *(bf16*)(PldsB + (((size_t)ql * 128 + kkl * 2) ^ ((ql & 7) << 4))) =
                    (bf16)p[kt][r];
            }
        bf16x8 pa[2];
#pragma unroll
        for (int ksl = 0; ksl < 2; ++ksl)
            pa[ksl] = *(const bf16x8*)(PldsB +
                (((size_t)lr * 128 + ksl * 64 + lg * 16) ^ ((lr & 7) << 4)));

#pragma unroll
        for (int dt = 0; dt < 4; ++dt) {
            int row = dt * 16 + lr;
#pragma unroll
            for (int ksl = 0; ksl < 2; ++ksl) {
                bf16x8 bv = *(const bf16x8*)(VtB +
                    (((size_t)row * 128 + ksl * 64 + lg * 16) ^ ((row & 7) << 4)));
                o[dt] = __builtin_amdgcn_mfma_f32_16x16x32_bf16(pa[ksl], bv, o[dt], 0, 0, 0);
            }
        }
        __syncthreads();
    }

#pragma unroll
    for (int dt = 0; dt < 4; ++dt) {
#pragma unroll
        for (int r = 0; r < 4; ++r) {
            int q = q0 + wave * 16 + lg * 4 + r;
            float denom = l_run[r];
            float val = denom > 0.f ? o[dt][r] / denom : 0.f;
            Op[(size_t)(b * S_LEN + q) * DMODEL + h * HDIM + dt * 16 + lr] = (bf16)val;
        }
    }
}

// ---------------------------------------------------------------------------
// y = LayerNorm(x_bf16 + rc_f32) * g + b ; writes f32 (optional) + bf16 (optional)
__global__ __launch_bounds__(256)
void ln_kernel(const bf16* __restrict__ x, const float* __restrict__ rc,
               const float* __restrict__ g, const float* __restrict__ beta,
               float* __restrict__ yf, bf16* __restrict__ yb) {
    const int row = blockIdx.x;
    const int tid = threadIdx.x;
    const int wave = tid >> 6, lane = tid & 63;
    const bf16* xr = x + (size_t)row * DMODEL;
    const float* rr = rc + (size_t)row * DMODEL;

    float v[4];
    {
        bf16x4 xv = *(const bf16x4*)(xr + tid * 4);
        f32x4 rv = *(const f32x4*)(rr + tid * 4);
#pragma unroll
        for (int i = 0; i < 4; ++i) v[i] = (float)xv[i] + rv[i];
    }
    float s = v[0] + v[1] + v[2] + v[3];
    float s2 = v[0] * v[0] + v[1] * v[1] + v[2] * v[2] + v[3] * v[3];
#pragma unroll
    for (int msk = 1; msk < 64; msk <<= 1) {
        s += __shfl_xor(s, msk);
        s2 += __shfl_xor(s2, msk);
    }
    __shared__ float red[8];
    if (lane == 0) { red[wave] = s; red[4 + wave] = s2; }
    __syncthreads();
    float ts = red[0] + red[1] + red[2] + red[3];
    float ts2 = red[4] + red[5] + red[6] + red[7];
    float mean = ts * (1.f / DMODEL);
    float var = ts2 * (1.f / DMODEL) - mean * mean;
    float inv = rsqrtf(var + 1e-5f);
#pragma unroll
    for (int i = 0; i < 4; ++i) {
        int c = tid * 4 + i;
        float yv = (v[i] - mean) * inv * g[c] + beta[c];
        if (yf) yf[(size_t)row * DMODEL + c] = yv;
        if (yb) yb[(size_t)row * DMODEL + c] = (bf16)yv;
    }
}

// ---------------------------------------------------------------------------
// Final LN fused with split-K reduce: h = relu(P0+P1+bias); out = LN(h + rc).
// (Skips the bf16 round-trip of h -> better precision, one less pass.)
__global__ __launch_bounds__(256)
void ln_splitk(const float* __restrict__ P0, const float* __restrict__ P1,
               const float* __restrict__ bias, const float* __restrict__ rc,
               const float* __restrict__ g, const float* __restrict__ beta,
               float* __restrict__ yf) {
    const int row = blockIdx.x;
    const int tid = threadIdx.x;
    const int wave = tid >> 6, lane = tid & 63;
    const size_t off = (size_t)row * DMODEL + tid * 4;

    f32x4 a = *(const f32x4*)(P0 + off);
    f32x4 bb = *(const f32x4*)(P1 + off);
    f32x4 bi = *(const f32x4*)(bias + tid * 4);
    f32x4 rv = *(const f32x4*)(rc + off);
    float v[4];
#pragma unroll
    for (int i = 0; i < 4; ++i) {
        float h = a[i] + bb[i] + bi[i];
        h = h > 0.f ? h : 0.f;
        v[i] = h + rv[i];
    }
    float s = v[0] + v[1] + v[2] + v[3];
    float s2 = v[0] * v[0] + v[1] * v[1] + v[2] * v[2] + v[3] * v[3];
#pragma unroll
    for (int msk = 1; msk < 64; msk <<= 1) {
        s += __shfl_xor(s, msk);
        s2 += __shfl_xor(s2, msk);
    }
    __shared__ float red[8];
    if (lane == 0) { red[wave] = s; red[4 + wave] = s2; }
    __syncthreads();
    float ts = red[0] + red[1] + red[2] + red[3];
    float ts2 = red[4] + red[5] + red[6] + red[7];
    float mean = ts * (1.f / DMODEL);
    float var = ts2 * (1.f / DMODEL) - mean * mean;
    float inv = rsqrtf(var + 1e-5f);
#pragma unroll
    for (int i = 0; i < 4; ++i) {
        int c = tid * 4 + i;
        yf[(size_t)row * DMODEL + c] = (v[i] - mean) * inv * g[c] + beta[c];
    }
}

// ---------------------------------------------------------------------------
extern "C" void kernel_launch(void* const* d_in, const int* in_sizes, int n_in,
                              void* d_out, int out_size, void* d_ws, size_t ws_size,
                              hipStream_t stream) {
    const float* en     = (const float*)d_in[0];
    const float* fr     = (const float*)d_in[1];
    const float* W_attn = (const float*)d_in[2];
    const float* b_attn = (const float*)d_in[3];
    const float* W_Q    = (const float*)d_in[4];
    const float* b_Q    = (const float*)d_in[5];
    const float* W_KV   = (const float*)d_in[6];
    const float* b_KV   = (const float*)d_in[7];
    const float* ln_g   = (const float*)d_in[8];
    const float* ln_b   = (const float*)d_in[9];
    const float* W1     = (const float*)d_in[10];
    const float* b1     = (const float*)d_in[11];
    const float* W2     = (const float*)d_in[12];
    const float* b2     = (const float*)d_in[13];
    const int* l_en     = (const int*)d_in[14];
    const int* l_fr     = (const int*)d_in[15];
    float* out = (float*)d_out;

    char* ws = (char*)d_ws;
    const size_t MB = (size_t)1 << 20;
    bf16* Wt_attn = (bf16*)(ws + 0);        //  6 MB (dead after dual-gemm; P0 reuse)
    bf16* Wt_Q    = (bf16*)(ws + 6 * MB);   //  2 MB (dead after cross-Q gemm)
    bf16* Wt_KV   = (bf16*)(ws + 8 * MB);   //  4 MB (dead after dual-gemm)
    bf16* Wt_1    = (bf16*)(ws + 12 * MB);  //  8 MB (dead after FFN1)
    bf16* Wt_2    = (bf16*)(ws + 20 * MB);  //  8 MB (live through FFN2 splitk)
    bf16* fr_bf   = (bf16*)(ws + 28 * MB);  //  8 MB (dead after dual-gemm; P1 reuse)
    bf16* en_bf   = (bf16*)(ws + 36 * MB);  //  8 MB (dead after dual-gemm; P1 reuse)
    bf16* bigA    = (bf16*)(ws + 44 * MB);  // 32 MB: qkv | qc | h
    bf16* xbuf    = (bf16*)(ws + 76 * MB);  //  8 MB: x1 | x2
    float* fr2    = (float*)(ws + 84 * MB); // 16 MB
    float* fr3    = (float*)(ws + 100 * MB);// 16 MB (kvc lives here until LN2)
    bf16* fbx     = (bf16*)(ws + 116 * MB); //  8 MB: fr2_bf then fr3_bf
    // split-K partials (stream-order-safe reuse):
    float* P0 = (float*)(ws + 0);           // 16 MB over Wt_attn/Q/KV/Wt_1[0:4MB]
    float* P1 = (float*)(ws + 28 * MB);     // 16 MB over fr_bf/en_bf
    bf16* kvc = (bf16*)(ws + 100 * MB);     // 16 MB, overwritten by fr3 at LN2
    // total 124 MB

    dim3 blk(256);

    cvt_two<<<dim3(8192), blk, 0, stream>>>(fr, fr_bf, en, en_bf, MROWS * DMODEL / 4);
    wconv_all<<<dim3(14336), blk, 0, stream>>>(W_attn, Wt_attn, W_Q, Wt_Q,
                                               W_KV, Wt_KV, W1, Wt_1, W2, Wt_2);

    // --- fused: self-attn QKV proj (768 wg) + cross KV proj (512 wg) ---
    bf16* qkv = bigA;  // [4096][3072]
    GemmArgs gq{fr_bf, Wt_attn, b_attn, qkv, 3072, 1024, 24};
    GemmArgs gk{en_bf, Wt_KV, b_KV, kvc, 2048, 1024, 16};
    gemm_dual<<<dim3(1280), blk, 0, stream>>>(gq, 768, gk);

    // --- self attention ---
    attn_flash<true><<<dim3(16, NHEAD, BATCH), blk, 0, stream>>>(
        qkv, 3072, qkv + 1024, 3072, qkv + 2048, 3072, l_fr, l_fr, xbuf);
    ln_kernel<<<dim3(4096), blk, 0, stream>>>(xbuf, fr, ln_g, ln_b, fr2, fbx);

    // --- cross attention ---
    bf16* qc = bigA;  // [4096][1024] (qkv dead after attn1)
    gemm_one<false><<<dim3(256), blk, 0, stream>>>(fbx, Wt_Q, b_Q, qc, 1024, 1024, 8);
    attn_flash<false><<<dim3(16, NHEAD, BATCH), blk, 0, stream>>>(
        qc, 1024, kvc, 2048, kvc + 1024, 2048, l_fr, l_en, xbuf);
    ln_kernel<<<dim3(4096), blk, 0, stream>>>(xbuf, fr2, ln_g, ln_b, fr3, fbx);

    // --- FFN ---
    bf16* h = bigA;  // [4096][4096]
    gemm_one<true><<<dim3(1024), blk, 0, stream>>>(fbx, Wt_1, b1, h, 4096, 1024, 32);
    gemm_splitk2<<<dim3(512), blk, 0, stream>>>(h, Wt_2, P0, P1, 1024, 4096, 8, 256);
    ln_splitk<<<dim3(4096), blk, 0, stream>>>(P0, P1, b2, fr3, ln_g, ln_b, out);
}

// Round 6
// 306.370 us; speedup vs baseline: 1.3632x; 1.1158x over previous
//
#include <hip/hip_runtime.h>
#include <hip/hip_bf16.h>
#include <cstdint>
#include <cstddef>

#define S_LEN  1024
#define DMODEL 1024
#define NHEAD  16
#define HDIM   64
#define BATCH  4
#define MROWS  (BATCH * S_LEN)   // 4096

typedef __bf16 bf16;
typedef __attribute__((ext_vector_type(8))) __bf16 bf16x8;
typedef __attribute__((ext_vector_type(4))) __bf16 bf16x4;
typedef __attribute__((ext_vector_type(4))) float f32x4;
typedef __attribute__((ext_vector_type(4))) unsigned int u32x4;

// ---------------------------------------------------------------------------
// async global->LDS, 16B per lane. LDS dest must be wave-uniform base.
__device__ __forceinline__ void async_load16(const void* g, void* l) {
    __builtin_amdgcn_global_load_lds(
        (const __attribute__((address_space(1))) unsigned int*)g,
        (__attribute__((address_space(3))) unsigned int*)l,
        16, 0, 0);
}

// ---------------------------------------------------------------------------
// Fused prep: blocks [0,8192) convert fr/en f32->bf16; [8192,22528) transpose
// the 5 weight matrices W[K][N] f32 -> Wt[N][K] bf16 (32x32 LDS tiles).
__global__ __launch_bounds__(256)
void prep_all(const float* __restrict__ fr, bf16* __restrict__ fr_bf,
              const float* __restrict__ en, bf16* __restrict__ en_bf,
              const float* __restrict__ Wa, bf16* __restrict__ Ta,
              const float* __restrict__ Wq, bf16* __restrict__ Tq,
              const float* __restrict__ Wkv, bf16* __restrict__ Tkv,
              const float* __restrict__ W1, bf16* __restrict__ T1,
              const float* __restrict__ W2, bf16* __restrict__ T2) {
    __shared__ float t[32][33];
    int id = blockIdx.x;
    if (id < 8192) {
        const int n4 = MROWS * DMODEL / 4;
        int i = id * 256 + threadIdx.x;
        const float* in = fr; bf16* out = fr_bf;
        if (i >= n4) { i -= n4; in = en; out = en_bf; }
        f32x4 v = ((const f32x4*)in)[i];
        bf16x4 o;
#pragma unroll
        for (int e = 0; e < 4; ++e) o[e] = (bf16)v[e];
        ((bf16x4*)out)[i] = o;
        return;
    }
    id -= 8192;
    const float* W; bf16* Wt; int K, N, nx, base;
    if (id < 3072)       { W = Wa;  Wt = Ta;  K = 1024; N = 3072; nx = 96;  base = 0; }
    else if (id < 4096)  { W = Wq;  Wt = Tq;  K = 1024; N = 1024; nx = 32;  base = 3072; }
    else if (id < 6144)  { W = Wkv; Wt = Tkv; K = 1024; N = 2048; nx = 64;  base = 4096; }
    else if (id < 10240) { W = W1;  Wt = T1;  K = 1024; N = 4096; nx = 128; base = 6144; }
    else                 { W = W2;  Wt = T2;  K = 4096; N = 1024; nx = 32;  base = 10240; }
    int loc = id - base;
    int n0 = (loc % nx) * 32, k0 = (loc / nx) * 32;
    int tx = threadIdx.x & 31, ty = threadIdx.x >> 5;  // 32 x 8
#pragma unroll
    for (int j = 0; j < 4; ++j)
        t[ty + j * 8][tx] = W[(size_t)(k0 + ty + j * 8) * N + n0 + tx];
    __syncthreads();
#pragma unroll
    for (int j = 0; j < 4; ++j)
        Wt[(size_t)(n0 + ty + j * 8) * K + k0 + tx] = (bf16)t[tx][ty + j * 8];
}

// ---------------------------------------------------------------------------
// GEMM core: 128x128 tile, BK=32, 4 waves (2x2), 2-buffer pipeline (issue
// next-tile global_load_lds before consuming current; __syncthreads drains).
__device__ __forceinline__ void gemm_acc(const bf16* __restrict__ A,
                                         const bf16* __restrict__ Bt,
                                         int Klen, int lda, int ldb,
                                         bf16* Alds, bf16* Blds,  // each [2][128*32]
                                         f32x4 acc[4][4]) {
    const int tid = threadIdx.x;
    const int wave = tid >> 6, lane = tid & 63;
    const int wr = wave >> 1, wc = wave & 1;
    const int lr = lane & 15, lg = lane >> 4, lk = lg * 8;
    const int srow = lane >> 2, scol = (lane & 3) * 8;

    const bf16* Aw = A + (size_t)(wave * 32 + srow) * lda + scol;
    const bf16* Bw = Bt + (size_t)(wave * 32 + srow) * ldb + scol;
    const int ldsw = (wave * 32) * 32;

    // prologue stage (buf 0)
    async_load16(Aw, Alds + ldsw);
    async_load16(Aw + (size_t)16 * lda, Alds + ldsw + 16 * 32);
    async_load16(Bw, Blds + ldsw);
    async_load16(Bw + (size_t)16 * ldb, Blds + ldsw + 16 * 32);
    __syncthreads();

    const int nt = Klen >> 5;
    for (int t = 0; t < nt; ++t) {
        const int cur = t & 1;
        if (t + 1 < nt) {
            const size_t k0 = (size_t)(t + 1) << 5;
            bf16* Ad = Alds + (cur ^ 1) * (128 * 32) + ldsw;
            bf16* Bd = Blds + (cur ^ 1) * (128 * 32) + ldsw;
            async_load16(Aw + k0, Ad);
            async_load16(Aw + (size_t)16 * lda + k0, Ad + 16 * 32);
            async_load16(Bw + k0, Bd);
            async_load16(Bw + (size_t)16 * ldb + k0, Bd + 16 * 32);
        }
        const bf16* Ab = Alds + cur * (128 * 32);
        const bf16* Bb = Blds + cur * (128 * 32);
        bf16x8 af[4], bfv[4];
#pragma unroll
        for (int i = 0; i < 4; ++i) {
            af[i]  = *(const bf16x8*)&Ab[(wr * 64 + i * 16 + lr) * 32 + lk];
            bfv[i] = *(const bf16x8*)&Bb[(wc * 64 + i * 16 + lr) * 32 + lk];
        }
#pragma unroll
        for (int mi = 0; mi < 4; ++mi)
#pragma unroll
            for (int ni = 0; ni < 4; ++ni)
                acc[mi][ni] = __builtin_amdgcn_mfma_f32_16x16x32_bf16(
                    af[mi], bfv[ni], acc[mi][ni], 0, 0, 0);
        __syncthreads();
    }
}

template<bool RELU>
__device__ __forceinline__ void epi_bf16(bf16* __restrict__ C, const float* __restrict__ bias,
                                         int N, int m0, int n0, f32x4 acc[4][4]) {
    const int tid = threadIdx.x;
    const int wave = tid >> 6, lane = tid & 63;
    const int wr = wave >> 1, wc = wave & 1;
    const int lr = lane & 15, lg = lane >> 4;
#pragma unroll
    for (int ni = 0; ni < 4; ++ni) {
        int n = n0 + wc * 64 + ni * 16 + lr;
        float bn = bias[n];
#pragma unroll
        for (int mi = 0; mi < 4; ++mi)
#pragma unroll
            for (int r = 0; r < 4; ++r) {
                int m = m0 + wr * 64 + mi * 16 + lg * 4 + r;
                float v = acc[mi][ni][r] + bn;
                if (RELU) v = v > 0.f ? v : 0.f;
                C[(size_t)m * N + n] = (bf16)v;
            }
    }
}

// M-tile skip: rows of this 128-tile are never consumed downstream
// (K/V rows >= round64(L[b]) never read; Q rows >= L[b] output-masked to 0).
__device__ __forceinline__ bool tile_dead(const int* Lm, int m0) {
    if (!Lm) return false;
    int cap = (Lm[m0 >> 10] + 63) & ~63;
    return (m0 & 1023) >= cap;
}

// ---------------------------------------------------------------------------
// Single GEMM, 1-D grid, XCD-swizzled (grid must be %8==0).
template<bool RELU>
__global__ __launch_bounds__(256, 2)
void gemm_one(const bf16* __restrict__ A, const bf16* __restrict__ Bt,
              const float* __restrict__ bias, bf16* __restrict__ C,
              int N, int K, int gx, const int* __restrict__ Lm) {
    __shared__ alignas(16) bf16 Alds[2][128 * 32];
    __shared__ alignas(16) bf16 Blds[2][128 * 32];
    const int nwg = gridDim.x;
    const int flat = blockIdx.x;
    const int swz = (flat & 7) * (nwg >> 3) + (flat >> 3);
    const int m0 = (swz / gx) * 128, n0 = (swz % gx) * 128;
    if (tile_dead(Lm, m0)) return;
    f32x4 acc[4][4] = {};
    gemm_acc(A + (size_t)m0 * K, Bt + (size_t)n0 * K, K, K, K,
             &Alds[0][0], &Blds[0][0], acc);
    epi_bf16<RELU>(C, bias, N, m0, n0, acc);
}

// ---------------------------------------------------------------------------
// Two independent GEMMs in one launch (shared K): blocks [0,nwg0) -> g0.
struct GemmArgs {
    const bf16* A; const bf16* Bt; const float* bias; bf16* C;
    int N; int K; int gx; const int* Lm;
};
__global__ __launch_bounds__(256, 2)
void gemm_dual(GemmArgs g0, int nwg0, GemmArgs g1) {
    __shared__ alignas(16) bf16 Alds[2][128 * 32];
    __shared__ alignas(16) bf16 Blds[2][128 * 32];
    const int nwg = gridDim.x;
    const int flat = blockIdx.x;
    const int swz = (flat & 7) * (nwg >> 3) + (flat >> 3);
    const bool first = swz < nwg0;
    const GemmArgs g = first ? g0 : g1;
    const int f = first ? swz : swz - nwg0;
    const int m0 = (f / g.gx) * 128, n0 = (f % g.gx) * 128;
    if (tile_dead(g.Lm, m0)) return;
    f32x4 acc[4][4] = {};
    gemm_acc(g.A + (size_t)m0 * g.K, g.Bt + (size_t)n0 * g.K, g.K, g.K, g.K,
             &Alds[0][0], &Blds[0][0], acc);
    epi_bf16<false>(g.C, g.bias, g.N, m0, n0, acc);
}

// ---------------------------------------------------------------------------
// Split-K GEMM (2 halves): writes f32 partials (no bias).
__global__ __launch_bounds__(256, 2)
void gemm_splitk2(const bf16* __restrict__ A, const bf16* __restrict__ Bt,
                  float* __restrict__ P0, float* __restrict__ P1,
                  int N, int K, int gx, int nwg_half) {
    __shared__ alignas(16) bf16 Alds[2][128 * 32];
    __shared__ alignas(16) bf16 Blds[2][128 * 32];
    const int nwg = gridDim.x;
    const int flat = blockIdx.x;
    const int swz = (flat & 7) * (nwg >> 3) + (flat >> 3);
    const int kz = swz >= nwg_half ? 1 : 0;
    const int f = swz - kz * nwg_half;
    const int m0 = (f / gx) * 128, n0 = (f % gx) * 128;
    const int Kh = K >> 1;
    const size_t koff = (size_t)kz * Kh;
    f32x4 acc[4][4] = {};
    gemm_acc(A + (size_t)m0 * K + koff, Bt + (size_t)n0 * K + koff, Kh, K, K,
             &Alds[0][0], &Blds[0][0], acc);
    float* P = kz ? P1 : P0;
    const int tid = threadIdx.x;
    const int wave = tid >> 6, lane = tid & 63;
    const int wr = wave >> 1, wc = wave & 1;
    const int lr = lane & 15, lg = lane >> 4;
#pragma unroll
    for (int ni = 0; ni < 4; ++ni) {
        int n = n0 + wc * 64 + ni * 16 + lr;
#pragma unroll
        for (int mi = 0; mi < 4; ++mi)
#pragma unroll
            for (int r = 0; r < 4; ++r) {
                int m = m0 + wr * 64 + mi * 16 + lg * 4 + r;
                P[(size_t)m * N + n] = acc[mi][ni][r];
            }
    }
}

// ---------------------------------------------------------------------------
// Flash attention, KVBLK=64, XOR-swizzled LDS (conflict-free b128 reads).
// One block = (b, h, 64 q-rows); 4 waves x 16 q-rows.
// scores = (Q K^T) / 32 (reference scales by sqrt(D)=32, not sqrt(HD)).
// mask: kk < lk && q < lq && (!CAUSAL || kk <= q); fully-masked row -> 0.
// Blocks with q0 >= lq are fully masked -> write zeros, exit.
template<bool CAUSAL>
__global__ __launch_bounds__(256, 4)
void attn_flash(const bf16* __restrict__ Qp, int qs,
                const bf16* __restrict__ Kp, int ks,
                const bf16* __restrict__ Vp, int vs,
                const int* __restrict__ Lq, const int* __restrict__ Lk,
                bf16* __restrict__ Op) {
    __shared__ alignas(16) bf16 Klds[64 * 64];
    __shared__ alignas(16) bf16 Vt[64 * 64];
    __shared__ alignas(16) bf16 Plds[4][16 * 64];

    const int tid = threadIdx.x;
    const int wave = tid >> 6, lane = tid & 63;
    const int qt = blockIdx.x, h = blockIdx.y, b = blockIdx.z;
    const int q0 = qt * 64;
    const int lq = Lq[b], lk = Lk[b];
    const int lr = lane & 15, lg = lane >> 4;

    if (q0 >= lq) {  // entire q-tile masked -> zeros
#pragma unroll
        for (int dt = 0; dt < 4; ++dt)
#pragma unroll
            for (int r = 0; r < 4; ++r) {
                int q = q0 + wave * 16 + lg * 4 + r;
                Op[(size_t)(b * S_LEN + q) * DMODEL + h * HDIM + dt * 16 + lr] = (bf16)0.f;
            }
        return;
    }

    char* KldsB = (char*)Klds;
    char* VtB = (char*)Vt;
    char* PldsB = (char*)&Plds[wave][0];

    bf16x8 aq[2];
    {
        const bf16* qrow = Qp + (size_t)(b * S_LEN + q0 + wave * 16 + lr) * qs + h * HDIM;
        aq[0] = *(const bf16x8*)(qrow + 0 + lg * 8);
        aq[1] = *(const bf16x8*)(qrow + 32 + lg * 8);
    }

    f32x4 o[4] = {};
    float m_run[4], l_run[4];
#pragma unroll
    for (int r = 0; r < 4; ++r) { m_run[r] = -INFINITY; l_run[r] = 0.f; }

    int kv_end = CAUSAL ? (q0 + 64) : S_LEN;
    int lk_cap = (lk + 63) & ~63;
    if (kv_end > lk_cap) kv_end = lk_cap;

    const int vk = lane;
    const int vd0 = wave * 16;

    for (int kk0 = 0; kk0 < kv_end; kk0 += 64) {
#pragma unroll
        for (int c = 0; c < 2; ++c) {
            int rloc = c * 8 + (lane >> 3);
            int row = wave * 16 + rloc;
            int chunk = (lane & 7) ^ (rloc & 7);
            async_load16(Kp + (size_t)(b * S_LEN + kk0 + row) * ks + h * HDIM + chunk * 8,
                         KldsB + (size_t)(wave * 16 + c * 8) * 128);
        }
        {
            const bf16* vsrc = Vp + (size_t)(b * S_LEN + kk0 + vk) * vs + h * HDIM + vd0;
            bf16x8 v0 = *(const bf16x8*)vsrc;
            bf16x8 v1 = *(const bf16x8*)(vsrc + 8);
#pragma unroll
            for (int e = 0; e < 8; ++e) {
                int d0 = vd0 + e, d1 = vd0 + 8 + e;
                *(bf16*)(VtB + (((size_t)d0 * 128 + vk * 2) ^ ((d0 & 7) << 4))) = v0[e];
                *(bf16*)(VtB + (((size_t)d1 * 128 + vk * 2) ^ ((d1 & 7) << 4))) = v1[e];
            }
        }
        __syncthreads();

        f32x4 sa[4];
#pragma unroll
        for (int kt = 0; kt < 4; ++kt) {
            int row = kt * 16 + lr;
            f32x4 z = {};
#pragma unroll
            for (int ds_ = 0; ds_ < 2; ++ds_) {
                bf16x8 bk = *(const bf16x8*)(KldsB +
                    (((size_t)row * 128 + ds_ * 64 + lg * 16) ^ ((row & 7) << 4)));
                z = __builtin_amdgcn_mfma_f32_16x16x32_bf16(aq[ds_], bk, z, 0, 0, 0);
            }
            sa[kt] = z;
        }

        float p[4][4];
#pragma unroll
        for (int r = 0; r < 4; ++r) {
            int q = q0 + wave * 16 + lg * 4 + r;
            float best = -INFINITY;
#pragma unroll
            for (int kt = 0; kt < 4; ++kt) {
                int kk = kk0 + kt * 16 + lr;
                float s = sa[kt][r] * 0.03125f;
                bool ok = (q < lq) && (kk < lk) && (!CAUSAL || kk <= q);
                s = ok ? s : -INFINITY;
                p[kt][r] = s;
                best = fmaxf(best, s);
            }
#pragma unroll
            for (int msk = 1; msk < 16; msk <<= 1)
                best = fmaxf(best, __shfl_xor(best, msk));
            float mn = fmaxf(m_run[r], best);
            float alpha = (m_run[r] == -INFINITY) ? 0.0f : __expf(m_run[r] - mn);
            float rs = 0.f;
#pragma unroll
            for (int kt = 0; kt < 4; ++kt) {
                float s = p[kt][r];
                float e = (s == -INFINITY) ? 0.f : __expf(s - mn);
                p[kt][r] = e;
                rs += e;
            }
#pragma unroll
            for (int msk = 1; msk < 16; msk <<= 1)
                rs += __shfl_xor(rs, msk);
            l_run[r] = l_run[r] * alpha + rs;
            m_run[r] = mn;
#pragma unroll
            for (int dt = 0; dt < 4; ++dt) o[dt][r] *= alpha;
        }

#pragma unroll
        for (int kt = 0; kt < 4; ++kt)
#pragma unroll
            for (int r = 0; r < 4; ++r) {
                int ql = lg * 4 + r, kkl = kt * 16 + lr;
                *(bf16*)(PldsB + (((size_t)ql * 128 + kkl * 2) ^ ((ql & 7) << 4))) =
                    (bf16)p[kt][r];
            }
        bf16x8 pa[2];
#pragma unroll
        for (int ksl = 0; ksl < 2; ++ksl)
            pa[ksl] = *(const bf16x8*)(PldsB +
                (((size_t)lr * 128 + ksl * 64 + lg * 16) ^ ((lr & 7) << 4)));

#pragma unroll
        for (int dt = 0; dt < 4; ++dt) {
            int row = dt * 16 + lr;
#pragma unroll
            for (int ksl = 0; ksl < 2; ++ksl) {
                bf16x8 bv = *(const bf16x8*)(VtB +
                    (((size_t)row * 128 + ksl * 64 + lg * 16) ^ ((row & 7) << 4)));
                o[dt] = __builtin_amdgcn_mfma_f32_16x16x32_bf16(pa[ksl], bv, o[dt], 0, 0, 0);
            }
        }
        __syncthreads();
    }

#pragma unroll
    for (int dt = 0; dt < 4; ++dt) {
#pragma unroll
        for (int r = 0; r < 4; ++r) {
            int q = q0 + wave * 16 + lg * 4 + r;
            float denom = l_run[r];
            float val = denom > 0.f ? o[dt][r] / denom : 0.f;
            Op[(size_t)(b * S_LEN + q) * DMODEL + h * HDIM + dt * 16 + lr] = (bf16)val;
        }
    }
}

// ---------------------------------------------------------------------------
// y = LayerNorm(x_bf16 + rc_f32) * g + b ; writes f32 (optional) + bf16 (optional)
__global__ __launch_bounds__(256)
void ln_kernel(const bf16* __restrict__ x, const float* __restrict__ rc,
               const float* __restrict__ g, const float* __restrict__ beta,
               float* __restrict__ yf, bf16* __restrict__ yb) {
    const int row = blockIdx.x;
    const int tid = threadIdx.x;
    const int wave = tid >> 6, lane = tid & 63;
    const bf16* xr = x + (size_t)row * DMODEL;
    const float* rr = rc + (size_t)row * DMODEL;

    float v[4];
    {
        bf16x4 xv = *(const bf16x4*)(xr + tid * 4);
        f32x4 rv = *(const f32x4*)(rr + tid * 4);
#pragma unroll
        for (int i = 0; i < 4; ++i) v[i] = (float)xv[i] + rv[i];
    }
    float s = v[0] + v[1] + v[2] + v[3];
    float s2 = v[0] * v[0] + v[1] * v[1] + v[2] * v[2] + v[3] * v[3];
#pragma unroll
    for (int msk = 1; msk < 64; msk <<= 1) {
        s += __shfl_xor(s, msk);
        s2 += __shfl_xor(s2, msk);
    }
    __shared__ float red[8];
    if (lane == 0) { red[wave] = s; red[4 + wave] = s2; }
    __syncthreads();
    float ts = red[0] + red[1] + red[2] + red[3];
    float ts2 = red[4] + red[5] + red[6] + red[7];
    float mean = ts * (1.f / DMODEL);
    float var = ts2 * (1.f / DMODEL) - mean * mean;
    float inv = rsqrtf(var + 1e-5f);
#pragma unroll
    for (int i = 0; i < 4; ++i) {
        int c = tid * 4 + i;
        float yv = (v[i] - mean) * inv * g[c] + beta[c];
        if (yf) yf[(size_t)row * DMODEL + c] = yv;
        if (yb) yb[(size_t)row * DMODEL + c] = (bf16)yv;
    }
}

// ---------------------------------------------------------------------------
// Final LN fused with split-K reduce: h = relu(P0+P1+bias); out = LN(h + rc).
__global__ __launch_bounds__(256)
void ln_splitk(const float* __restrict__ P0, const float* __restrict__ P1,
               const float* __restrict__ bias, const float* __restrict__ rc,
               const float* __restrict__ g, const float* __restrict__ beta,
               float* __restrict__ yf) {
    const int row = blockIdx.x;
    const int tid = threadIdx.x;
    const int wave = tid >> 6, lane = tid & 63;
    const size_t off = (size_t)row * DMODEL + tid * 4;

    f32x4 a = *(const f32x4*)(P0 + off);
    f32x4 bb = *(const f32x4*)(P1 + off);
    f32x4 bi = *(const f32x4*)(bias + tid * 4);
    f32x4 rv = *(const f32x4*)(rc + off);
    float v[4];
#pragma unroll
    for (int i = 0; i < 4; ++i) {
        float h = a[i] + bb[i] + bi[i];
        h = h > 0.f ? h : 0.f;
        v[i] = h + rv[i];
    }
    float s = v[0] + v[1] + v[2] + v[3];
    float s2 = v[0] * v[0] + v[1] * v[1] + v[2] * v[2] + v[3] * v[3];
#pragma unroll
    for (int msk = 1; msk < 64; msk <<= 1) {
        s += __shfl_xor(s, msk);
        s2 += __shfl_xor(s2, msk);
    }
    __shared__ float red[8];
    if (lane == 0) { red[wave] = s; red[4 + wave] = s2; }
    __syncthreads();
    float ts = red[0] + red[1] + red[2] + red[3];
    float ts2 = red[4] + red[5] + red[6] + red[7];
    float mean = ts * (1.f / DMODEL);
    float var = ts2 * (1.f / DMODEL) - mean * mean;
    float inv = rsqrtf(var + 1e-5f);
#pragma unroll
    for (int i = 0; i < 4; ++i) {
        int c = tid * 4 + i;
        yf[(size_t)row * DMODEL + c] = (v[i] - mean) * inv * g[c] + beta[c];
    }
}

// ---------------------------------------------------------------------------
extern "C" void kernel_launch(void* const* d_in, const int* in_sizes, int n_in,
                              void* d_out, int out_size, void* d_ws, size_t ws_size,
                              hipStream_t stream) {
    const float* en     = (const float*)d_in[0];
    const float* fr     = (const float*)d_in[1];
    const float* W_attn = (const float*)d_in[2];
    const float* b_attn = (const float*)d_in[3];
    const float* W_Q    = (const float*)d_in[4];
    const float* b_Q    = (const float*)d_in[5];
    const float* W_KV   = (const float*)d_in[6];
    const float* b_KV   = (const float*)d_in[7];
    const float* ln_g   = (const float*)d_in[8];
    const float* ln_b   = (const float*)d_in[9];
    const float* W1     = (const float*)d_in[10];
    const float* b1     = (const float*)d_in[11];
    const float* W2     = (const float*)d_in[12];
    const float* b2     = (const float*)d_in[13];
    const int* l_en     = (const int*)d_in[14];
    const int* l_fr     = (const int*)d_in[15];
    float* out = (float*)d_out;

    char* ws = (char*)d_ws;
    const size_t MB = (size_t)1 << 20;
    bf16* Wt_attn = (bf16*)(ws + 0);        //  6 MB (dead after dual-gemm; P0 reuse)
    bf16* Wt_Q    = (bf16*)(ws + 6 * MB);   //  2 MB (dead after cross-Q gemm)
    bf16* Wt_KV   = (bf16*)(ws + 8 * MB);   //  4 MB (dead after dual-gemm)
    bf16* Wt_1    = (bf16*)(ws + 12 * MB);  //  8 MB (dead after FFN1)
    bf16* Wt_2    = (bf16*)(ws + 20 * MB);  //  8 MB (live through FFN2 splitk)
    bf16* fr_bf   = (bf16*)(ws + 28 * MB);  //  8 MB (dead after dual-gemm; P1 reuse)
    bf16* en_bf   = (bf16*)(ws + 36 * MB);  //  8 MB (dead after dual-gemm; P1 reuse)
    bf16* bigA    = (bf16*)(ws + 44 * MB);  // 32 MB: qkv | qc | h
    bf16* xbuf    = (bf16*)(ws + 76 * MB);  //  8 MB: x1 | x2
    float* fr2    = (float*)(ws + 84 * MB); // 16 MB
    float* fr3    = (float*)(ws + 100 * MB);// 16 MB (kvc lives here until LN2)
    bf16* fbx     = (bf16*)(ws + 116 * MB); //  8 MB: fr2_bf then fr3_bf
    // split-K partials (stream-order-safe reuse):
    float* P0 = (float*)(ws + 0);           // 16 MB over Wt_attn/Q/KV/Wt_1[0:4MB]
    float* P1 = (float*)(ws + 28 * MB);     // 16 MB over fr_bf/en_bf
    bf16* kvc = (bf16*)(ws + 100 * MB);     // 16 MB, overwritten by fr3 at LN2
    // total 124 MB

    dim3 blk(256);

    prep_all<<<dim3(22528), blk, 0, stream>>>(fr, fr_bf, en, en_bf,
        W_attn, Wt_attn, W_Q, Wt_Q, W_KV, Wt_KV, W1, Wt_1, W2, Wt_2);

    // --- fused: self-attn QKV proj (768 wg) + cross KV proj (512 wg) ---
    bf16* qkv = bigA;  // [4096][3072]
    GemmArgs gq{fr_bf, Wt_attn, b_attn, qkv, 3072, 1024, 24, l_fr};
    GemmArgs gk{en_bf, Wt_KV, b_KV, kvc, 2048, 1024, 16, l_en};
    gemm_dual<<<dim3(1280), blk, 0, stream>>>(gq, 768, gk);

    // --- self attention ---
    attn_flash<true><<<dim3(16, NHEAD, BATCH), blk, 0, stream>>>(
        qkv, 3072, qkv + 1024, 3072, qkv + 2048, 3072, l_fr, l_fr, xbuf);
    ln_kernel<<<dim3(4096), blk, 0, stream>>>(xbuf, fr, ln_g, ln_b, fr2, fbx);

    // --- cross attention ---
    bf16* qc = bigA;  // [4096][1024] (qkv dead after attn1)
    gemm_one<false><<<dim3(256), blk, 0, stream>>>(fbx, Wt_Q, b_Q, qc, 1024, 1024, 8, l_fr);
    attn_flash<false><<<dim3(16, NHEAD, BATCH), blk, 0, stream>>>(
        qc, 1024, kvc, 2048, kvc + 1024, 2048, l_fr, l_en, xbuf);
    ln_kernel<<<dim3(4096), blk, 0, stream>>>(xbuf, fr2, ln_g, ln_b, fr3, fbx);

    // --- FFN ---
    bf16* h = bigA;  // [4096][4096]
    gemm_one<true><<<dim3(1024), blk, 0, stream>>>(fbx, Wt_1, b1, h, 4096, 1024, 32, nullptr);
    gemm_splitk2<<<dim3(512), blk, 0, stream>>>(h, Wt_2, P0, P1, 1024, 4096, 8, 256);
    ln_splitk<<<dim3(4096), blk, 0, stream>>>(P0, P1, b2, fr3, ln_g, ln_b, out);
}